// Round 1
// baseline (2279.455 us; speedup 1.0000x reference)
//
#include <hip/hip_runtime.h>
#include <stdint.h>

// ---------------------------------------------------------------------------
// TopkQuantLayer: out = scatter(quant(top 25% by |x|)), n = 32*1024*1024 fp32.
//
// Strategy: histogram-based exact radix selection, no sorting.
//  - 22-bit signed-sortable-key histogram H[4M] over all of x (one pass).
//  - abs-key bins map to signed bins: pos = 0x200000+a, neg = 0x1FFFFF-a, so
//    the same histogram serves |x| top-k threshold AND signed order stats.
//  - kept-set order stat at kept-rank r == full-array order stat at rank r
//    (r < num_pos) else n-k+r  (value multisets; proof in analysis).
//  - exact threshold bit pattern t + stable lowest-index tie selection
//    (matches jax.lax.top_k); quant params from 16 exact order statistics.
// ws need: ~19.4 MB.
// ---------------------------------------------------------------------------

#define NBIN      (1u<<22)
#define NCHUNK    4096
#define NSLOT_MAX 40
#define SLOT_CAP  8192
#define MAX_TIES  1024

// ctl word offsets
#define CTL_ASTAR    0
#define CTL_RR2      1
#define CTL_CNTABOVE 2
#define CTL_NSLOT    3
#define CTL_TKEY     4
#define CTL_NTIES    5
#define CTL_SLOTBIN  8
#define CTL_CANDSLOT 48
#define CTL_CANDRES  80
#define CTL_BND      112
#define CTL_MN       120
#define CTL_MX       128
#define CTL_STEP     136
#define CTL_TIEIDX   144
#define CTL_SIZE     1200

__device__ __forceinline__ uint32_t skey(uint32_t b){
  // ascending-sortable unsigned key for signed float bits
  return (b & 0x80000000u) ? ~b : (b | 0x80000000u);
}

// inclusive suffix sums in LDS: a[i] = sum_{j>=i} a[j]; uniform-control helper
__device__ void suffix_scan(uint32_t* a, uint32_t* tmp, int L){
  for (int d = 1; d < L; d <<= 1){
    for (int i = threadIdx.x; i < L; i += blockDim.x)
      tmp[i] = a[i] + ((i + d < L) ? a[i + d] : 0u);
    __syncthreads();
    for (int i = threadIdx.x; i < L; i += blockDim.x) a[i] = tmp[i];
    __syncthreads();
  }
}

// find lo = max{ i : suf[i] > R }  (suf[L] == 0 virtual); requires suf[0] > R
__device__ int suf_search(const uint32_t* suf, int L, uint32_t R){
  int lo = 0, hi = L;
  while (hi - lo > 1){
    int mid = (lo + hi) >> 1;
    uint32_t s = (mid < L) ? suf[mid] : 0u;
    if (s > R) lo = mid; else hi = mid;
  }
  return lo;
}

// ---------------- pass 1: 22-bit signed-key histogram ----------------------
__global__ void k_hist(const uint32_t* __restrict__ xb, uint32_t* __restrict__ H, int n4){
  int i = blockIdx.x * blockDim.x + threadIdx.x;
  if (i >= n4) return;
  uint4 v = ((const uint4*)xb)[i];
  atomicAdd(&H[skey(v.x) >> 10], 1u);
  atomicAdd(&H[skey(v.y) >> 10], 1u);
  atomicAdd(&H[skey(v.z) >> 10], 1u);
  atomicAdd(&H[skey(v.w) >> 10], 1u);
}

// ---------------- chunk sums (1024 bins per chunk) -------------------------
__global__ void k_chunks(const uint32_t* __restrict__ H, uint32_t* __restrict__ C){
  uint32_t base = blockIdx.x * 1024u;
  uint32_t s = 0;
  for (int j = threadIdx.x; j < 1024; j += 256) s += H[base + j];
  for (int o = 32; o; o >>= 1) s += __shfl_down(s, o);
  __shared__ uint32_t r4[4];
  int wid = threadIdx.x >> 6, lane = threadIdx.x & 63;
  if (lane == 0) r4[wid] = s;
  __syncthreads();
  if (threadIdx.x == 0) C[blockIdx.x] = r4[0] + r4[1] + r4[2] + r4[3];
}

// ---------------- single-block: locate abs threshold bin + candidate bins --
__global__ __launch_bounds__(1024) void k_s1(const uint32_t* __restrict__ H,
    const uint32_t* __restrict__ C, uint32_t* __restrict__ ctl,
    uint32_t k, uint32_t c, uint32_t n){
  __shared__ uint32_t sA[4096];
  __shared__ uint32_t sT[4096];
  __shared__ uint32_t candBin[32], candRes[32];
  int tid = threadIdx.x;

  // Phase A: abs-key selection (chunk level). abs-chunk j = pos chunk 2048+j + neg chunk 2047-j
  for (int j = tid; j < 2048; j += 1024) sA[j] = C[2048 + j] + C[2047 - j];
  __syncthreads();
  suffix_scan(sA, sT, 2048);
  uint32_t R = k - 1u;                       // descending abs rank of t
  int jstar = suf_search(sA, 2048, R);
  uint32_t aboveCh = (jstar + 1 < 2048) ? sA[jstar + 1] : 0u;
  uint32_t rr = R - aboveCh;
  __syncthreads();
  // within-chunk abs bins
  for (int al = tid; al < 1024; al += 1024){
    uint32_t ab = (uint32_t)jstar * 1024u + (uint32_t)al;
    sA[al] = H[0x200000u + ab] + H[0x1FFFFFu - ab];
  }
  __syncthreads();
  suffix_scan(sA, sT, 1024);
  int alstar = suf_search(sA, 1024, rr);
  uint32_t wAbove = (alstar + 1 < 1024) ? sA[alstar + 1] : 0u;
  uint32_t aStar = (uint32_t)jstar * 1024u + (uint32_t)alstar; // 21-bit abs prefix of t
  uint32_t rr2 = rr - wAbove;                                  // rank within abs bin
  uint32_t cntAbove = aboveCh + wAbove;                        // #elements with abs-prefix > aStar
  if (tid == 0){
    ctl[CTL_ASTAR] = aStar; ctl[CTL_RR2] = rr2; ctl[CTL_CNTABOVE] = cntAbove;
  }
  __syncthreads();

  // Phase B: signed candidate bins for 32 static ranks:
  //   cand<16 : full rank = keptRank  (used when keptRank <  num_pos)
  //   cand>=16: full rank = n-k+keptRank (used when keptRank >= num_pos)
  // keptRank(i): i<8 -> i*c (mx_p), i>=8 -> (i-7)*c - 1 (mn_p)
  for (int j = tid; j < 4096; j += 1024) sA[j] = C[j];
  __syncthreads();
  suffix_scan(sA, sT, 4096);
  int prevChunk = -1;
  for (int cand = 0; cand < 32; cand++){
    int i = cand & 15;
    uint32_t kr = (i < 8) ? (uint32_t)i * c : (uint32_t)(i - 7) * c - 1u;
    uint32_t Rr = (cand < 16) ? kr : (n - k + kr);
    int q = suf_search(sA, 4096, Rr);
    uint32_t aboveC = (q + 1 < 4096) ? sA[q + 1] : 0u;
    uint32_t Rp = Rr - aboveC;
    if (q != prevChunk){
      __syncthreads();
      for (int b = tid; b < 1024; b += 1024) sT[b] = H[(uint32_t)q * 1024u + (uint32_t)b];
      __syncthreads();
      suffix_scan(sT, sT + 2048, 1024);
      prevChunk = q;
    }
    int bl = suf_search(sT, 1024, Rp);
    uint32_t aboveB = (bl + 1 < 1024) ? sT[bl + 1] : 0u;
    if (tid == 0){ candBin[cand] = (uint32_t)q * 1024u + (uint32_t)bl; candRes[cand] = Rp - aboveB; }
  }
  __syncthreads();

  // Phase C: dedupe bins -> gather slots. t's two bins are slots 0 and 1.
  if (tid == 0){
    uint32_t bins[NSLOT_MAX]; int nS = 0;
    bins[nS++] = 0x200000u + aStar;   // slot 0: positives with abs-prefix aStar
    bins[nS++] = 0x1FFFFFu - aStar;   // slot 1: negatives with abs-prefix aStar
    for (int cd = 0; cd < 32; cd++){
      uint32_t b = candBin[cd]; int s = -1;
      for (int t2 = 0; t2 < nS; t2++) if (bins[t2] == b){ s = t2; break; }
      if (s < 0){ s = nS; bins[nS++] = b; }
      ctl[CTL_CANDSLOT + cd] = (uint32_t)s;
      ctl[CTL_CANDRES + cd]  = candRes[cd];
    }
    ctl[CTL_NSLOT] = (uint32_t)nS;
    for (int s = 0; s < nS; s++) ctl[CTL_SLOTBIN + s] = bins[s];
  }
}

// ---------------- pass 2: gather elements in candidate bins ----------------
__global__ void k_gather(const uint32_t* __restrict__ xb, const uint32_t* __restrict__ ctl,
    uint32_t* __restrict__ slotCnt, uint64_t* __restrict__ slotBuf, int n4){
  __shared__ uint32_t sBins[NSLOT_MAX];
  __shared__ uint32_t bloom[32];
  __shared__ uint32_t sNS;
  int tid = threadIdx.x;
  if (tid == 0) sNS = ctl[CTL_NSLOT];
  if (tid < 32) bloom[tid] = 0u;
  __syncthreads();
  uint32_t nS = sNS;
  if (tid < (int)nS){
    uint32_t b = ctl[CTL_SLOTBIN + tid];
    sBins[tid] = b;
    uint32_t h = b & 1023u;
    atomicOr(&bloom[h >> 5], 1u << (h & 31u));
  }
  __syncthreads();
  int i = blockIdx.x * blockDim.x + tid;
  if (i >= n4) return;
  uint4 v = ((const uint4*)xb)[i];
  uint32_t bv[4] = {v.x, v.y, v.z, v.w};
  uint32_t base = (uint32_t)i * 4u;
  #pragma unroll
  for (int j = 0; j < 4; j++){
    uint32_t key = skey(bv[j]);
    uint32_t bin = key >> 10;
    uint32_t h = bin & 1023u;
    if (bloom[h >> 5] & (1u << (h & 31u))){
      for (uint32_t s = 0; s < nS; s++){
        if (sBins[s] == bin){
          uint32_t pos = atomicAdd(&slotCnt[s], 1u);
          if (pos < SLOT_CAP)
            slotBuf[(size_t)s * SLOT_CAP + pos] = ((uint64_t)key << 32) | (uint64_t)(base + j);
          break;
        }
      }
    }
  }
}

// ---------------- single-block: resolve t, ties, num_pos, boundaries -------
__global__ __launch_bounds__(1024) void k_s2(const uint32_t* __restrict__ H,
    const uint32_t* __restrict__ C, uint32_t* __restrict__ ctl,
    const uint32_t* __restrict__ slotCnt, const uint64_t* __restrict__ slotBuf,
    uint32_t k, uint32_t c, uint32_t n){
  __shared__ uint32_t sH[1024];
  __shared__ uint32_t sS[1024];
  __shared__ uint32_t sT[1024];
  __shared__ uint32_t red[1024];
  __shared__ uint32_t tieIdx[MAX_TIES];
  __shared__ uint8_t  tieSgn[MAX_TIES];
  __shared__ uint32_t sCnt[4];
  __shared__ float    tv[16];
  int tid = threadIdx.x;
  uint32_t aStar = ctl[CTL_ASTAR], rr2 = ctl[CTL_RR2], cntAbove = ctl[CTL_CNTABOVE];
  uint32_t cntP = slotCnt[0]; if (cntP > SLOT_CAP) cntP = SLOT_CAP;
  uint32_t cntN = slotCnt[1]; if (cntN > SLOT_CAP) cntN = SLOT_CAP;

  // resolve low 10 bits of t: counting sort of abs-prefix-aStar elements
  for (int j = tid; j < 1024; j += 1024) sH[j] = 0u;
  __syncthreads();
  for (uint32_t e = tid; e < cntP; e += 1024){
    uint32_t key = (uint32_t)(slotBuf[e] >> 32);
    atomicAdd(&sH[key & 1023u], 1u);               // pos: key low10 == m low10
  }
  for (uint32_t e = tid; e < cntN; e += 1024){
    uint32_t key = (uint32_t)(slotBuf[SLOT_CAP + e] >> 32);
    uint32_t m = 0x7FFFFFFFu - key;                // neg: recover abs bits
    atomicAdd(&sH[m & 1023u], 1u);
  }
  __syncthreads();
  for (int j = tid; j < 1024; j += 1024) sS[j] = sH[j];
  __syncthreads();
  suffix_scan(sS, sT, 1024);
  int l = suf_search(sS, 1024, rr2);
  uint32_t w = (l + 1 < 1024) ? sS[l + 1] : 0u;
  uint32_t cnt_gt = cntAbove + w;                  // #{|x| > t}
  uint32_t r_ties = k - cnt_gt;                    // ties to keep (>=1)
  uint32_t t_key = (aStar << 10) | (uint32_t)l;    // exact |t| bit pattern

  // gather ties (abs bits == t_key), select r_ties smallest flat indices
  if (tid == 0){ sCnt[0] = 0u; sCnt[1] = 0u; sCnt[2] = 0u; }
  __syncthreads();
  for (uint32_t e = tid; e < cntP; e += 1024){
    uint64_t ent = slotBuf[e];
    uint32_t key = (uint32_t)(ent >> 32);
    if ((key & 1023u) == (uint32_t)l){
      uint32_t p = atomicAdd(&sCnt[0], 1u);
      if (p < MAX_TIES){ tieIdx[p] = (uint32_t)ent; tieSgn[p] = 1; }
    }
  }
  for (uint32_t e = tid; e < cntN; e += 1024){
    uint64_t ent = slotBuf[SLOT_CAP + e];
    uint32_t key = (uint32_t)(ent >> 32);
    uint32_t m = 0x7FFFFFFFu - key;
    if ((m & 1023u) == (uint32_t)l){
      uint32_t p = atomicAdd(&sCnt[0], 1u);
      if (p < MAX_TIES){ tieIdx[p] = (uint32_t)ent; tieSgn[p] = 0; }
    }
  }
  __syncthreads();
  uint32_t mT = sCnt[0]; if (mT > MAX_TIES) mT = MAX_TIES;
  for (uint32_t e = tid; e < mT; e += 1024){
    uint32_t my = tieIdx[e];
    uint32_t rank = 0;
    for (uint32_t f = 0; f < mT; f++) rank += (tieIdx[f] < my) ? 1u : 0u;
    if (rank < r_ties){
      uint32_t p = atomicAdd(&sCnt[1], 1u);
      if (p < MAX_TIES) ctl[CTL_TIEIDX + p] = my;
      if (tieSgn[e]) atomicAdd(&sCnt[2], 1u);
    }
  }
  __syncthreads();
  uint32_t nSel = sCnt[1]; if (nSel > MAX_TIES) nSel = MAX_TIES;
  uint32_t selPos = sCnt[2];

  // num_pos = #{x > t} + selected positive ties
  uint32_t binPos = 0x200000u + aStar;
  uint32_t q0 = binPos >> 10;
  uint32_t lb = binPos & 1023u;
  uint32_t part = 0;
  for (uint32_t q = q0 + 1u + (uint32_t)tid; q < 4096u; q += 1024u) part += C[q];
  for (uint32_t b = lb + 1u + (uint32_t)tid; b < 1024u; b += 1024u) part += H[q0 * 1024u + b];
  for (uint32_t e = tid; e < cntP; e += 1024){
    uint32_t key = (uint32_t)(slotBuf[e] >> 32);
    if ((key & 1023u) > (uint32_t)l) part++;
  }
  red[tid] = part;
  __syncthreads();
  for (int o = 512; o; o >>= 1){ if (tid < o) red[tid] += red[tid + o]; __syncthreads(); }
  uint32_t num_pos = red[0] + selPos;
  __syncthreads();

  // resolve the 16 boundary values (mx_p = rank p*c, mn_p = rank (p+1)*c-1)
  for (int i = 0; i < 16; i++){
    uint32_t kr = (i < 8) ? (uint32_t)i * c : (uint32_t)(i - 7) * c - 1u;
    int cand = (kr < num_pos) ? i : (16 + i);
    uint32_t slot  = ctl[CTL_CANDSLOT + cand];
    uint32_t resid = ctl[CTL_CANDRES + cand];
    uint32_t bin   = ctl[CTL_SLOTBIN + slot];
    uint32_t cnt2  = slotCnt[slot]; if (cnt2 > SLOT_CAP) cnt2 = SLOT_CAP;
    __syncthreads();
    for (int j = tid; j < 1024; j += 1024) sH[j] = 0u;
    __syncthreads();
    for (uint32_t e = tid; e < cnt2; e += 1024){
      uint32_t key = (uint32_t)(slotBuf[(size_t)slot * SLOT_CAP + e] >> 32);
      atomicAdd(&sH[key & 1023u], 1u);
    }
    __syncthreads();
    suffix_scan(sH, sT, 1024);
    int bl = suf_search(sH, 1024, resid);
    uint32_t fullkey = (bin << 10) | (uint32_t)bl;
    uint32_t bits = (fullkey & 0x80000000u) ? (fullkey ^ 0x80000000u) : ~fullkey; // un-skey
    if (tid == 0) tv[i] = __uint_as_float(bits);
  }
  __syncthreads();

  if (tid == 0){
    ctl[CTL_TKEY] = t_key;
    ctl[CTL_NTIES] = nSel;
    for (int j = 1; j < 8; j++) ctl[CTL_BND + (j - 1)] = __float_as_uint(tv[j]); // b_1..b_7 = mx_1..mx_7
    for (int p = 0; p < 8; p++){
      float mx = tv[p], mn = tv[8 + p];
      ctl[CTL_MN + p] = __float_as_uint(mn);
      ctl[CTL_MX + p] = __float_as_uint(mx);
      ctl[CTL_STEP + p] = __float_as_uint((mx - mn) / 255.0f);  // fp32, as reference
    }
  }
}

// ---------------- pass 3: write quantized output ---------------------------
__global__ void k_out(const uint32_t* __restrict__ xb, float* __restrict__ out,
    const uint32_t* __restrict__ ctl, int n4){
  __shared__ float sB[7], sMn[8], sMx[8], sSt[8];
  __shared__ uint32_t sTK, sNT;
  __shared__ uint32_t sTie[MAX_TIES];
  int tid = threadIdx.x;
  if (tid == 0){ sTK = ctl[CTL_TKEY]; sNT = ctl[CTL_NTIES]; }
  if (tid < 7) sB[tid] = __uint_as_float(ctl[CTL_BND + tid]);
  if (tid < 8){
    sMn[tid] = __uint_as_float(ctl[CTL_MN + tid]);
    sMx[tid] = __uint_as_float(ctl[CTL_MX + tid]);
    sSt[tid] = __uint_as_float(ctl[CTL_STEP + tid]);
  }
  __syncthreads();
  uint32_t nt = sNT, tk = sTK;
  for (int e = tid; e < (int)nt; e += blockDim.x) sTie[e] = ctl[CTL_TIEIDX + e];
  __syncthreads();
  int i = blockIdx.x * blockDim.x + tid;
  if (i >= n4) return;
  uint4 v = ((const uint4*)xb)[i];
  uint32_t bv[4] = {v.x, v.y, v.z, v.w};
  float ov[4];
  uint32_t base = (uint32_t)i * 4u;
  #pragma unroll
  for (int j = 0; j < 4; j++){
    uint32_t b = bv[j];
    uint32_t m = b & 0x7FFFFFFFu;      // abs bits: monotone in |x|
    float q = 0.0f;
    bool keep = m > tk;
    if (m == tk){
      uint32_t idx = base + (uint32_t)j;
      for (uint32_t e = 0; e < nt; e++) if (sTie[e] == idx){ keep = true; break; }
    }
    if (keep){
      float x = __uint_as_float(b);
      int p = 0;
      #pragma unroll
      for (int j2 = 0; j2 < 7; j2++) p += (sB[j2] >= x) ? 1 : 0;  // partition = #{b_j >= v}
      float mn = sMn[p], mx = sMx[p], st = sSt[p];
      if (mn == mx) q = x;                                        // passthrough chunk
      else {
        float sst = (st == 0.0f) ? 1.0f : st;                     // safe_step, as reference
        q = rintf((x - mn) / sst) * st + mn;                      // round-half-even == jnp.round
      }
    }
    ov[j] = q;
  }
  ((float4*)out)[i] = make_float4(ov[0], ov[1], ov[2], ov[3]);
}

// ---------------------------------------------------------------------------
extern "C" void kernel_launch(void* const* d_in, const int* in_sizes, int n_in,
                              void* d_out, int out_size, void* d_ws, size_t ws_size,
                              hipStream_t stream){
  const uint32_t* xb = (const uint32_t*)d_in[0];
  float* out = (float*)d_out;
  uint32_t n = (uint32_t)in_sizes[0];
  uint32_t k = n / 4u;       // static keep count (RATIO = 0.25)
  uint32_t c = k / 8u;       // partition size

  uint32_t* H       = (uint32_t*)d_ws;            // 4M bins
  uint32_t* C       = H + NBIN;                   // 4096 chunk sums
  uint32_t* ctl     = C + NCHUNK;                 // control block
  uint32_t* slotCnt = ctl + CTL_SIZE;             // NSLOT_MAX counters
  uint64_t* slotBuf = (uint64_t*)(slotCnt + NSLOT_MAX); // byte offset % 8 == 0

  size_t zeroBytes = (size_t)(NBIN + NCHUNK + CTL_SIZE + NSLOT_MAX) * 4u;
  size_t needed = zeroBytes + (size_t)NSLOT_MAX * SLOT_CAP * 8u;  // ~19.4 MB
  if (ws_size < needed){
    hipMemsetAsync(d_out, 0, (size_t)out_size * 4u, stream);      // loud failure, no corruption
    return;
  }
  hipMemsetAsync(d_ws, 0, zeroBytes, stream);

  int n4 = (int)(n / 4u);
  int blocks = (n4 + 255) / 256;
  k_hist  <<<blocks, 256, 0, stream>>>(xb, H, n4);
  k_chunks<<<NCHUNK, 256, 0, stream>>>(H, C);
  k_s1    <<<1, 1024, 0, stream>>>(H, C, ctl, k, c, n);
  k_gather<<<blocks, 256, 0, stream>>>(xb, ctl, slotCnt, slotBuf, n4);
  k_s2    <<<1, 1024, 0, stream>>>(H, C, ctl, slotCnt, slotBuf, k, c, n);
  k_out   <<<blocks, 256, 0, stream>>>(xb, out, ctl, n4);
}

// Round 2
// 759.609 us; speedup vs baseline: 3.0008x; 3.0008x over previous
//
#include <hip/hip_runtime.h>
#include <stdint.h>

// ---------------------------------------------------------------------------
// TopkQuantLayer: out = scatter(quant(top 25% by |x|)), n = 32M fp32.
// R1: replace the global-atomic 22-bit histogram (1.5 ms, 1 GB of atomic
// write traffic) with hierarchical LDS-privatized histograms:
//   13-bit coarse (8192 bins, LDS, partial-array merge, NO global atomics)
//   -> select ~34 candidate 13-bit bins (1 block)
//   -> 9-bit LDS refine of candidates only (<=40 slots x 512, partials)
//   -> select 22-bit gather bins (1 block)
//   -> gather candidate-bin elements -> exact resolve -> output pass.
// ws need ~32.2 MB.
// ---------------------------------------------------------------------------

#define H13BINS   8192
#define P13       256      // hist13 grid (partial count)
#define P9        256      // hist9 grid
#define NSLOT_MAX 40
#define SLOT_CAP  8192
#define MAX_TIES  1024
#define GSL       16       // slots per scan-group in k_sel9

// ctl word offsets
#define CTL_ASTAR13   0
#define CTL_RRA       1
#define CTL_ABOVEA    2
#define CTL_NS13      3
#define CTL_POSAB13   4
#define CTL_TKEY      5
#define CTL_NTIES     6
#define CTL_RR2       7
#define CTL_CNTABOVE  8
#define CTL_POSABOVE  9
#define CTL_NSLOT     10
#define CTL_A21       11
#define CTL_S13BIN    16   // 40
#define CTL_C13SLOT   56   // 32
#define CTL_C13RES    88   // 32
#define CTL_SLOTBIN   120  // 40 (gather bin22 list)
#define CTL_CANDSLOT  160  // 32
#define CTL_CANDRES   192  // 32
#define CTL_BND       224  // 7
#define CTL_MN        232  // 8
#define CTL_MX        240  // 8
#define CTL_STEP      248  // 8
#define CTL_TIEIDX    256  // 1024
#define CTL_SIZE      1280

__device__ __forceinline__ uint32_t skey(uint32_t b){
  return (b & 0x80000000u) ? ~b : (b | 0x80000000u);   // ascending-sortable
}

// inclusive suffix scan, one segment of width L (L<=8192), block-wide Hillis
__device__ void scan1(uint32_t* a, uint32_t* tmp, int L){
  for (int d = 1; d < L; d <<= 1){
    for (int i = threadIdx.x; i < L; i += blockDim.x)
      tmp[i] = a[i] + ((i + d < L) ? a[i + d] : 0u);
    __syncthreads();
    for (int i = threadIdx.x; i < L; i += blockDim.x) a[i] = tmp[i];
    __syncthreads();
  }
}

// segmented inclusive suffix scan: nseg segments of width 512
__device__ void scan_seg512(uint32_t* a, uint32_t* tmp, int total){
  for (int d = 1; d < 512; d <<= 1){
    for (int i = threadIdx.x; i < total; i += blockDim.x){
      int j = i & 511;
      tmp[i] = a[i] + ((j + d < 512) ? a[i + d] : 0u);
    }
    __syncthreads();
    for (int i = threadIdx.x; i < total; i += blockDim.x) a[i] = tmp[i];
    __syncthreads();
  }
}

// lo = max{ i : suf[i] > R } (virtual suf[L]=0); requires suf[0] > R
__device__ int suf_search(const uint32_t* suf, int L, uint32_t R){
  int lo = 0, hi = L;
  while (hi - lo > 1){
    int mid = (lo + hi) >> 1;
    uint32_t s = (mid < L) ? suf[mid] : 0u;
    if (s > R) lo = mid; else hi = mid;
  }
  return lo;
}

// ---------------- pass 1: coarse 13-bit histogram (LDS, partials) ----------
__global__ __launch_bounds__(1024) void k_hist13(const uint32_t* __restrict__ xb,
    uint32_t* __restrict__ part13, int n4){
  __shared__ uint32_t h[H13BINS];
  int tid = threadIdx.x;
  for (int i = tid; i < H13BINS; i += 1024) h[i] = 0u;
  __syncthreads();
  int stride = gridDim.x * blockDim.x;
  for (int i = blockIdx.x * blockDim.x + tid; i < n4; i += stride){
    uint4 v = ((const uint4*)xb)[i];
    atomicAdd(&h[skey(v.x) >> 19], 1u);
    atomicAdd(&h[skey(v.y) >> 19], 1u);
    atomicAdd(&h[skey(v.z) >> 19], 1u);
    atomicAdd(&h[skey(v.w) >> 19], 1u);
  }
  __syncthreads();
  uint32_t* dst = part13 + (size_t)blockIdx.x * H13BINS;
  for (int i = tid; i < H13BINS; i += 1024) dst[i] = h[i];
}

__global__ void k_red13(const uint32_t* __restrict__ part13, uint32_t* __restrict__ H13){
  int b = blockIdx.x * blockDim.x + threadIdx.x;   // 8192 threads
  uint32_t s = 0;
  for (int p = 0; p < P13; p++) s += part13[(size_t)p * H13BINS + b];
  H13[b] = s;
}

// ---------------- single block: select candidate 13-bit bins ---------------
__global__ __launch_bounds__(1024) void k_sel13(const uint32_t* __restrict__ H13,
    uint32_t* __restrict__ ctl, uint8_t* __restrict__ table13,
    uint32_t k, uint32_t c, uint32_t n){
  __shared__ uint32_t sA[8192];
  __shared__ uint32_t sT[8192];
  __shared__ uint32_t sAbs[4096];
  __shared__ uint32_t cBin13[32], cRes[32];
  __shared__ uint32_t shv[4];   // 0:astar13 1:rrA 2:aboveA 3:nS
  int tid = threadIdx.x;

  // Phase A: abs selection at 13-bit level
  for (int a = tid; a < 4096; a += 1024) sAbs[a] = H13[4096 + a] + H13[4095 - a];
  __syncthreads();
  scan1(sAbs, sT, 4096);
  if (tid == 0){
    int astar = suf_search(sAbs, 4096, k - 1u);
    uint32_t aboveA = (astar + 1 < 4096) ? sAbs[astar + 1] : 0u;
    shv[0] = (uint32_t)astar; shv[1] = (k - 1u) - aboveA; shv[2] = aboveA;
  }
  __syncthreads();
  uint32_t astar13 = shv[0];

  // Phase B: signed suffix scan + 32 candidate ranks
  for (int i = tid; i < 8192; i += 1024) sA[i] = H13[i];
  __syncthreads();
  scan1(sA, sT, 8192);
  uint32_t posThr13 = 4096u + astar13;
  if (tid < 32){
    int i = tid & 15;
    uint32_t kr = (i < 8) ? (uint32_t)i * c : (uint32_t)(i - 7) * c - 1u;
    uint32_t Rr = (tid < 16) ? kr : (n - k + kr);
    int q = suf_search(sA, 8192, Rr);
    uint32_t aboveC = (q + 1 < 8192) ? sA[q + 1] : 0u;
    cBin13[tid] = (uint32_t)q;
    cRes[tid] = Rr - aboveC;
  }
  __syncthreads();

  if (tid == 0){
    uint32_t bins[NSLOT_MAX]; int nS = 0;
    bins[nS++] = posThr13;            // slot 0 = pos threshold 13-bin
    bins[nS++] = 4095u - astar13;     // slot 1 = neg threshold 13-bin
    for (int cd = 0; cd < 32; cd++){
      uint32_t b = cBin13[cd]; int s = -1;
      for (int t2 = 0; t2 < nS; t2++) if (bins[t2] == b){ s = t2; break; }
      if (s < 0){ s = nS; bins[nS++] = b; }
      ctl[CTL_C13SLOT + cd] = (uint32_t)s;
      ctl[CTL_C13RES + cd]  = cRes[cd];
    }
    for (int s = 0; s < nS; s++) ctl[CTL_S13BIN + s] = bins[s];
    ctl[CTL_NS13] = (uint32_t)nS;
    ctl[CTL_ASTAR13] = astar13;
    ctl[CTL_RRA] = shv[1];
    ctl[CTL_ABOVEA] = shv[2];
    ctl[CTL_POSAB13] = (posThr13 + 1u < 8192u) ? sA[posThr13 + 1] : 0u;
    shv[3] = (uint32_t)nS;
  }
  __syncthreads();
  // bin13 -> slot+1 lookup table (8192 bytes)
  for (int i = tid; i < 2048; i += 1024) ((uint32_t*)table13)[i] = 0u;
  __syncthreads();
  uint32_t nS = shv[3];
  if (tid < (int)nS) table13[ctl[CTL_S13BIN + tid]] = (uint8_t)(tid + 1);
}

// ---------------- pass 2: refine candidate bins to 22 bits (LDS) -----------
__global__ __launch_bounds__(1024) void k_hist9(const uint32_t* __restrict__ xb,
    const uint8_t* __restrict__ table13, const uint32_t* __restrict__ ctl,
    uint32_t* __restrict__ part9, int n4){
  __shared__ uint8_t tb[H13BINS];
  __shared__ uint32_t fine[NSLOT_MAX * 512];
  __shared__ uint32_t snS;
  int tid = threadIdx.x;
  for (int i = tid; i < 2048; i += 1024) ((uint32_t*)tb)[i] = ((const uint32_t*)table13)[i];
  if (tid == 0) snS = ctl[CTL_NS13];
  __syncthreads();
  int L = (int)snS * 512;
  for (int i = tid; i < L; i += 1024) fine[i] = 0u;
  __syncthreads();
  int stride = gridDim.x * blockDim.x;
  for (int i = blockIdx.x * blockDim.x + tid; i < n4; i += stride){
    uint4 v = ((const uint4*)xb)[i];
    uint32_t bv[4] = {v.x, v.y, v.z, v.w};
    #pragma unroll
    for (int j = 0; j < 4; j++){
      uint32_t key = skey(bv[j]);
      uint32_t s = tb[key >> 19];
      if (s) atomicAdd(&fine[(s - 1u) * 512u + ((key >> 10) & 511u)], 1u);
    }
  }
  __syncthreads();
  uint32_t* dst = part9 + (size_t)blockIdx.x * (NSLOT_MAX * 512);
  for (int i = tid; i < L; i += 1024) dst[i] = fine[i];
}

__global__ void k_red9(const uint32_t* __restrict__ part9,
    const uint32_t* __restrict__ ctl, uint32_t* __restrict__ H9){
  int L = (int)ctl[CTL_NS13] * 512;
  int b = blockIdx.x * blockDim.x + threadIdx.x;   // NSLOT_MAX*512 threads
  if (b >= L) return;
  uint32_t s = 0;
  for (int p = 0; p < P9; p++) s += part9[(size_t)p * (NSLOT_MAX * 512) + b];
  H9[b] = s;
}

// ---------------- single block: resolve 22-bit gather bins -----------------
__global__ __launch_bounds__(1024) void k_sel9(const uint32_t* __restrict__ H9,
    uint32_t* __restrict__ ctl){
  __shared__ uint32_t fine[GSL * 512];
  __shared__ uint32_t tmp[GSL * 512];
  __shared__ uint32_t absF[512], absT[512];
  __shared__ uint32_t s13bin[NSLOT_MAX];
  __shared__ uint32_t cSlot[32], cRes[32], cBin22[32], cRes2[32];
  __shared__ uint32_t sh[4];  // 0:jstar9 1:rr2 2:cntAbove 3:posAbove
  int tid = threadIdx.x;
  uint32_t nS = ctl[CTL_NS13];
  uint32_t astar13 = ctl[CTL_ASTAR13], rrA = ctl[CTL_RRA], aboveA = ctl[CTL_ABOVEA];
  if (tid < (int)NSLOT_MAX) s13bin[tid] = ctl[CTL_S13BIN + tid];
  if (tid < 32){ cSlot[tid] = ctl[CTL_C13SLOT + tid]; cRes[tid] = ctl[CTL_C13RES + tid]; }
  __syncthreads();

  for (uint32_t g0 = 0; g0 < nS; g0 += GSL){
    uint32_t gn = nS - g0; if (gn > GSL) gn = GSL;
    int L = (int)gn * 512;
    for (int i = tid; i < L; i += 1024) fine[i] = H9[g0 * 512u + (uint32_t)i];
    __syncthreads();
    if (g0 == 0){
      // abs refine from raw slot0/slot1 fine hists
      for (int j = tid; j < 512; j += 1024) absF[j] = fine[j] + fine[512 + 511 - j];
      __syncthreads();
      scan1(absF, absT, 512);
      if (tid == 0){
        int j = suf_search(absF, 512, rrA);
        uint32_t ab9 = (j + 1 < 512) ? absF[j + 1] : 0u;
        sh[0] = (uint32_t)j; sh[1] = rrA - ab9; sh[2] = aboveA + ab9;
      }
      __syncthreads();
    }
    scan_seg512(fine, tmp, L);
    if (g0 == 0 && tid == 0){
      uint32_t j = sh[0];
      uint32_t pfa = (j + 1u < 512u) ? fine[j + 1u] : 0u;   // slot0 suffix above jstar9
      sh[3] = ctl[CTL_POSAB13] + pfa;
    }
    if (tid < 32){
      uint32_t s = cSlot[tid];
      if (s >= g0 && s < g0 + gn){
        uint32_t* seg = fine + (s - g0) * 512u;
        int bl = suf_search(seg, 512, cRes[tid]);
        uint32_t ab = (bl + 1 < 512) ? seg[bl + 1] : 0u;
        cBin22[tid] = (s13bin[s] << 9) | (uint32_t)bl;
        cRes2[tid] = cRes[tid] - ab;
      }
    }
    __syncthreads();
  }

  if (tid == 0){
    uint32_t jstar9 = sh[0];
    uint32_t posBin22 = ((4096u + astar13) << 9) | jstar9;
    uint32_t negBin22 = ((4095u - astar13) << 9) | (511u - jstar9);
    uint32_t bins[NSLOT_MAX]; int nG = 0;
    bins[nG++] = posBin22;
    bins[nG++] = negBin22;
    for (int cd = 0; cd < 32; cd++){
      uint32_t b = cBin22[cd]; int s = -1;
      for (int t2 = 0; t2 < nG; t2++) if (bins[t2] == b){ s = t2; break; }
      if (s < 0){ s = nG; bins[nG++] = b; }
      ctl[CTL_CANDSLOT + cd] = (uint32_t)s;
      ctl[CTL_CANDRES + cd]  = cRes2[cd];
    }
    ctl[CTL_NSLOT] = (uint32_t)nG;
    for (int s = 0; s < nG; s++) ctl[CTL_SLOTBIN + s] = bins[s];
    ctl[CTL_RR2] = sh[1];
    ctl[CTL_CNTABOVE] = sh[2];
    ctl[CTL_POSABOVE] = sh[3];
    ctl[CTL_A21] = (astar13 << 9) | jstar9;
  }
}

// ---------------- pass 3: gather elements in candidate 22-bit bins ---------
__global__ void k_gather(const uint32_t* __restrict__ xb, const uint32_t* __restrict__ ctl,
    uint32_t* __restrict__ slotCnt, uint64_t* __restrict__ slotBuf, int n4){
  __shared__ uint32_t sBins[NSLOT_MAX];
  __shared__ uint32_t bloom[32];
  __shared__ uint32_t sNS;
  int tid = threadIdx.x;
  if (tid == 0) sNS = ctl[CTL_NSLOT];
  if (tid < 32) bloom[tid] = 0u;
  __syncthreads();
  uint32_t nS = sNS;
  if (tid < (int)nS){
    uint32_t b = ctl[CTL_SLOTBIN + tid];
    sBins[tid] = b;
    uint32_t h = b & 1023u;
    atomicOr(&bloom[h >> 5], 1u << (h & 31u));
  }
  __syncthreads();
  int i = blockIdx.x * blockDim.x + tid;
  if (i >= n4) return;
  uint4 v = ((const uint4*)xb)[i];
  uint32_t bv[4] = {v.x, v.y, v.z, v.w};
  uint32_t base = (uint32_t)i * 4u;
  #pragma unroll
  for (int j = 0; j < 4; j++){
    uint32_t key = skey(bv[j]);
    uint32_t bin = key >> 10;
    uint32_t h = bin & 1023u;
    if (bloom[h >> 5] & (1u << (h & 31u))){
      for (uint32_t s = 0; s < nS; s++){
        if (sBins[s] == bin){
          uint32_t pos = atomicAdd(&slotCnt[s], 1u);
          if (pos < SLOT_CAP)
            slotBuf[(size_t)s * SLOT_CAP + pos] = ((uint64_t)key << 32) | (uint64_t)(base + j);
          break;
        }
      }
    }
  }
}

// ---------------- single block: exact t, ties, num_pos, boundaries ---------
__global__ __launch_bounds__(1024) void k_s2(uint32_t* __restrict__ ctl,
    const uint32_t* __restrict__ slotCnt, const uint64_t* __restrict__ slotBuf,
    uint32_t k, uint32_t c){
  __shared__ uint32_t sH[1024];
  __shared__ uint32_t sS[1024];
  __shared__ uint32_t sT[1024];
  __shared__ uint32_t red[1024];
  __shared__ uint32_t tieIdx[MAX_TIES];
  __shared__ uint8_t  tieSgn[MAX_TIES];
  __shared__ uint32_t sCnt[4];
  __shared__ float    tv[16];
  int tid = threadIdx.x;
  uint32_t a21 = ctl[CTL_A21], rr2 = ctl[CTL_RR2], cntAbove = ctl[CTL_CNTABOVE];
  uint32_t cntP = slotCnt[0]; if (cntP > SLOT_CAP) cntP = SLOT_CAP;
  uint32_t cntN = slotCnt[1]; if (cntN > SLOT_CAP) cntN = SLOT_CAP;

  // resolve low 10 bits of |t|
  for (int j = tid; j < 1024; j += 1024) sH[j] = 0u;
  __syncthreads();
  for (uint32_t e = tid; e < cntP; e += 1024){
    uint32_t key = (uint32_t)(slotBuf[e] >> 32);
    atomicAdd(&sH[key & 1023u], 1u);
  }
  for (uint32_t e = tid; e < cntN; e += 1024){
    uint32_t key = (uint32_t)(slotBuf[SLOT_CAP + e] >> 32);
    uint32_t m = 0x7FFFFFFFu - key;
    atomicAdd(&sH[m & 1023u], 1u);
  }
  __syncthreads();
  for (int j = tid; j < 1024; j += 1024) sS[j] = sH[j];
  __syncthreads();
  scan1(sS, sT, 1024);
  int l = suf_search(sS, 1024, rr2);
  uint32_t w = (l + 1 < 1024) ? sS[l + 1] : 0u;
  uint32_t cnt_gt = cntAbove + w;
  uint32_t r_ties = k - cnt_gt;
  uint32_t t_key = (a21 << 10) | (uint32_t)l;

  // collect ties, keep r_ties smallest flat indices (stable, as jax top_k)
  if (tid == 0){ sCnt[0] = 0u; sCnt[1] = 0u; sCnt[2] = 0u; }
  __syncthreads();
  for (uint32_t e = tid; e < cntP; e += 1024){
    uint64_t ent = slotBuf[e];
    uint32_t key = (uint32_t)(ent >> 32);
    if ((key & 1023u) == (uint32_t)l){
      uint32_t p = atomicAdd(&sCnt[0], 1u);
      if (p < MAX_TIES){ tieIdx[p] = (uint32_t)ent; tieSgn[p] = 1; }
    }
  }
  for (uint32_t e = tid; e < cntN; e += 1024){
    uint64_t ent = slotBuf[SLOT_CAP + e];
    uint32_t key = (uint32_t)(ent >> 32);
    uint32_t m = 0x7FFFFFFFu - key;
    if ((m & 1023u) == (uint32_t)l){
      uint32_t p = atomicAdd(&sCnt[0], 1u);
      if (p < MAX_TIES){ tieIdx[p] = (uint32_t)ent; tieSgn[p] = 0; }
    }
  }
  __syncthreads();
  uint32_t mT = sCnt[0]; if (mT > MAX_TIES) mT = MAX_TIES;
  for (uint32_t e = tid; e < mT; e += 1024){
    uint32_t my = tieIdx[e];
    uint32_t rank = 0;
    for (uint32_t f = 0; f < mT; f++) rank += (tieIdx[f] < my) ? 1u : 0u;
    if (rank < r_ties){
      uint32_t p = atomicAdd(&sCnt[1], 1u);
      if (p < MAX_TIES) ctl[CTL_TIEIDX + p] = my;
      if (tieSgn[e]) atomicAdd(&sCnt[2], 1u);
    }
  }
  __syncthreads();
  uint32_t nSel = sCnt[1]; if (nSel > MAX_TIES) nSel = MAX_TIES;
  uint32_t selPos = sCnt[2];

  // num_pos = #{x > |t|} + selected positive ties
  uint32_t part = 0;
  for (uint32_t e = tid; e < cntP; e += 1024){
    uint32_t key = (uint32_t)(slotBuf[e] >> 32);
    if ((key & 1023u) > (uint32_t)l) part++;
  }
  red[tid] = part;
  __syncthreads();
  for (int o = 512; o; o >>= 1){ if (tid < o) red[tid] += red[tid + o]; __syncthreads(); }
  uint32_t num_pos = red[0] + ctl[CTL_POSABOVE] + selPos;
  __syncthreads();

  // resolve the 16 boundary values (mx_p = kept rank p*c, mn_p = (p+1)*c-1)
  for (int i = 0; i < 16; i++){
    uint32_t kr = (i < 8) ? (uint32_t)i * c : (uint32_t)(i - 7) * c - 1u;
    int cand = (kr < num_pos) ? i : (16 + i);
    uint32_t slot  = ctl[CTL_CANDSLOT + cand];
    uint32_t resid = ctl[CTL_CANDRES + cand];
    uint32_t bin   = ctl[CTL_SLOTBIN + slot];
    uint32_t cnt2  = slotCnt[slot]; if (cnt2 > SLOT_CAP) cnt2 = SLOT_CAP;
    __syncthreads();
    for (int j = tid; j < 1024; j += 1024) sH[j] = 0u;
    __syncthreads();
    for (uint32_t e = tid; e < cnt2; e += 1024){
      uint32_t key = (uint32_t)(slotBuf[(size_t)slot * SLOT_CAP + e] >> 32);
      atomicAdd(&sH[key & 1023u], 1u);
    }
    __syncthreads();
    scan1(sH, sT, 1024);
    int bl = suf_search(sH, 1024, resid);
    uint32_t fullkey = (bin << 10) | (uint32_t)bl;
    uint32_t bits = (fullkey & 0x80000000u) ? (fullkey ^ 0x80000000u) : ~fullkey;
    if (tid == 0) tv[i] = __uint_as_float(bits);
    __syncthreads();
  }

  if (tid == 0){
    ctl[CTL_TKEY] = t_key;
    ctl[CTL_NTIES] = nSel;
    for (int j = 1; j < 8; j++) ctl[CTL_BND + (j - 1)] = __float_as_uint(tv[j]);
    for (int p = 0; p < 8; p++){
      float mx = tv[p], mn = tv[8 + p];
      ctl[CTL_MN + p] = __float_as_uint(mn);
      ctl[CTL_MX + p] = __float_as_uint(mx);
      ctl[CTL_STEP + p] = __float_as_uint((mx - mn) / 255.0f);
    }
  }
}

// ---------------- pass 4: write quantized output ---------------------------
__global__ void k_out(const uint32_t* __restrict__ xb, float* __restrict__ out,
    const uint32_t* __restrict__ ctl, int n4){
  __shared__ float sB[7], sMn[8], sMx[8], sSt[8];
  __shared__ uint32_t sTK, sNT;
  __shared__ uint32_t sTie[MAX_TIES];
  int tid = threadIdx.x;
  if (tid == 0){ sTK = ctl[CTL_TKEY]; sNT = ctl[CTL_NTIES]; }
  if (tid < 7) sB[tid] = __uint_as_float(ctl[CTL_BND + tid]);
  if (tid < 8){
    sMn[tid] = __uint_as_float(ctl[CTL_MN + tid]);
    sMx[tid] = __uint_as_float(ctl[CTL_MX + tid]);
    sSt[tid] = __uint_as_float(ctl[CTL_STEP + tid]);
  }
  __syncthreads();
  uint32_t nt = sNT, tk = sTK;
  for (int e = tid; e < (int)nt; e += blockDim.x) sTie[e] = ctl[CTL_TIEIDX + e];
  __syncthreads();
  int i = blockIdx.x * blockDim.x + tid;
  if (i >= n4) return;
  uint4 v = ((const uint4*)xb)[i];
  uint32_t bv[4] = {v.x, v.y, v.z, v.w};
  float ov[4];
  uint32_t base = (uint32_t)i * 4u;
  #pragma unroll
  for (int j = 0; j < 4; j++){
    uint32_t b = bv[j];
    uint32_t m = b & 0x7FFFFFFFu;
    float q = 0.0f;
    bool keep = m > tk;
    if (m == tk){
      uint32_t idx = base + (uint32_t)j;
      for (uint32_t e = 0; e < nt; e++) if (sTie[e] == idx){ keep = true; break; }
    }
    if (keep){
      float x = __uint_as_float(b);
      int p = 0;
      #pragma unroll
      for (int j2 = 0; j2 < 7; j2++) p += (sB[j2] >= x) ? 1 : 0;
      float mn = sMn[p], mx = sMx[p], st = sSt[p];
      if (mn == mx) q = x;
      else {
        float sst = (st == 0.0f) ? 1.0f : st;
        q = rintf((x - mn) / sst) * st + mn;
      }
    }
    ov[j] = q;
  }
  ((float4*)out)[i] = make_float4(ov[0], ov[1], ov[2], ov[3]);
}

// ---------------------------------------------------------------------------
extern "C" void kernel_launch(void* const* d_in, const int* in_sizes, int n_in,
                              void* d_out, int out_size, void* d_ws, size_t ws_size,
                              hipStream_t stream){
  const uint32_t* xb = (const uint32_t*)d_in[0];
  float* out = (float*)d_out;
  uint32_t n = (uint32_t)in_sizes[0];
  uint32_t k = n / 4u;
  uint32_t c = k / 8u;

  // ws layout (u32 units)
  uint32_t* w = (uint32_t*)d_ws;
  uint32_t* H13     = w;                            // 8192
  uint32_t* H9      = H13 + H13BINS;                // 40*512 = 20480
  uint8_t*  table13 = (uint8_t*)(H9 + NSLOT_MAX*512); // 8192 B (2048 u32)
  uint32_t* ctl     = (uint32_t*)(table13 + H13BINS); // 1280
  uint32_t* slotCnt = ctl + CTL_SIZE;               // 40
  uint64_t* slotBuf = (uint64_t*)(slotCnt + NSLOT_MAX); // 40*8192 u64
  uint32_t* part13  = (uint32_t*)(slotBuf + (size_t)NSLOT_MAX * SLOT_CAP);
  uint32_t* part9   = part13 + (size_t)P13 * H13BINS;
  size_t endu32 = (size_t)((uint32_t*)part9 - w) + (size_t)P9 * NSLOT_MAX * 512;
  if (ws_size < endu32 * 4u){
    hipMemsetAsync(d_out, 0, (size_t)out_size * 4u, stream);
    return;
  }
  // zero ctl + slotCnt (contiguous)
  hipMemsetAsync(ctl, 0, (size_t)(CTL_SIZE + NSLOT_MAX) * 4u, stream);

  int n4 = (int)(n / 4u);
  int blocksE = (n4 + 255) / 256;
  k_hist13<<<P13, 1024, 0, stream>>>(xb, part13, n4);
  k_red13 <<<H13BINS / 256, 256, 0, stream>>>(part13, H13);
  k_sel13 <<<1, 1024, 0, stream>>>(H13, ctl, table13, k, c, n);
  k_hist9 <<<P9, 1024, 0, stream>>>(xb, table13, ctl, part9, n4);
  k_red9  <<<(NSLOT_MAX * 512) / 256, 256, 0, stream>>>(part9, ctl, H9);
  k_sel9  <<<1, 1024, 0, stream>>>(H9, ctl);
  k_gather<<<blocksE, 256, 0, stream>>>(xb, ctl, slotCnt, slotBuf, n4);
  k_s2    <<<1, 1024, 0, stream>>>(ctl, slotCnt, slotBuf, k, c);
  k_out   <<<blocksE, 256, 0, stream>>>(xb, out, ctl, n4);
}

// Round 3
// 618.340 us; speedup vs baseline: 3.6864x; 1.2285x over previous
//
#include <hip/hip_runtime.h>
#include <stdint.h>

// ---------------------------------------------------------------------------
// TopkQuantLayer: out = scatter(quant(top 25% by |x|)), n = 32M fp32.
// R2: k_gather rewrite. The R1 bloom(10-bit)+linear-scan inner loop was
// divergence/latency-bound (268 us, 253 GB/s): ~90% of waves entered a <=34
// iteration dependent LDS scan. Replace with an open-addressed LDS hash table
// keyed on the full 22-bit bin (4096 entries, 0.8% load): one independent LDS
// probe per element. Slot appends aggregated per block in LDS (one global
// atomic per block x slot). Other kernels unchanged.
// ---------------------------------------------------------------------------

#define H13BINS   8192
#define P13       256      // hist13 grid (partial count)
#define P9        256      // hist9 grid
#define NSLOT_MAX 40
#define SLOT_CAP  8192
#define MAX_TIES  1024
#define GSL       16       // slots per scan-group in k_sel9
#define GATHER_BLOCKS 4096

// ctl word offsets
#define CTL_ASTAR13   0
#define CTL_RRA       1
#define CTL_ABOVEA    2
#define CTL_NS13      3
#define CTL_POSAB13   4
#define CTL_TKEY      5
#define CTL_NTIES     6
#define CTL_RR2       7
#define CTL_CNTABOVE  8
#define CTL_POSABOVE  9
#define CTL_NSLOT     10
#define CTL_A21       11
#define CTL_S13BIN    16   // 40
#define CTL_C13SLOT   56   // 32
#define CTL_C13RES    88   // 32
#define CTL_SLOTBIN   120  // 40 (gather bin22 list)
#define CTL_CANDSLOT  160  // 32
#define CTL_CANDRES   192  // 32
#define CTL_BND       224  // 7
#define CTL_MN        232  // 8
#define CTL_MX        240  // 8
#define CTL_STEP      248  // 8
#define CTL_TIEIDX    256  // 1024
#define CTL_SIZE      1280

__device__ __forceinline__ uint32_t skey(uint32_t b){
  return (b & 0x80000000u) ? ~b : (b | 0x80000000u);   // ascending-sortable
}

// inclusive suffix scan, one segment of width L (L<=8192), block-wide Hillis
__device__ void scan1(uint32_t* a, uint32_t* tmp, int L){
  for (int d = 1; d < L; d <<= 1){
    for (int i = threadIdx.x; i < L; i += blockDim.x)
      tmp[i] = a[i] + ((i + d < L) ? a[i + d] : 0u);
    __syncthreads();
    for (int i = threadIdx.x; i < L; i += blockDim.x) a[i] = tmp[i];
    __syncthreads();
  }
}

// segmented inclusive suffix scan: segments of width 512
__device__ void scan_seg512(uint32_t* a, uint32_t* tmp, int total){
  for (int d = 1; d < 512; d <<= 1){
    for (int i = threadIdx.x; i < total; i += blockDim.x){
      int j = i & 511;
      tmp[i] = a[i] + ((j + d < 512) ? a[i + d] : 0u);
    }
    __syncthreads();
    for (int i = threadIdx.x; i < total; i += blockDim.x) a[i] = tmp[i];
    __syncthreads();
  }
}

// lo = max{ i : suf[i] > R } (virtual suf[L]=0); requires suf[0] > R
__device__ int suf_search(const uint32_t* suf, int L, uint32_t R){
  int lo = 0, hi = L;
  while (hi - lo > 1){
    int mid = (lo + hi) >> 1;
    uint32_t s = (mid < L) ? suf[mid] : 0u;
    if (s > R) lo = mid; else hi = mid;
  }
  return lo;
}

// ---------------- pass 1: coarse 13-bit histogram (LDS, partials) ----------
__global__ __launch_bounds__(1024) void k_hist13(const uint32_t* __restrict__ xb,
    uint32_t* __restrict__ part13, int n4){
  __shared__ uint32_t h[H13BINS];
  int tid = threadIdx.x;
  for (int i = tid; i < H13BINS; i += 1024) h[i] = 0u;
  __syncthreads();
  int stride = gridDim.x * blockDim.x;
  for (int i = blockIdx.x * blockDim.x + tid; i < n4; i += stride){
    uint4 v = ((const uint4*)xb)[i];
    atomicAdd(&h[skey(v.x) >> 19], 1u);
    atomicAdd(&h[skey(v.y) >> 19], 1u);
    atomicAdd(&h[skey(v.z) >> 19], 1u);
    atomicAdd(&h[skey(v.w) >> 19], 1u);
  }
  __syncthreads();
  uint32_t* dst = part13 + (size_t)blockIdx.x * H13BINS;
  for (int i = tid; i < H13BINS; i += 1024) dst[i] = h[i];
}

__global__ void k_red13(const uint32_t* __restrict__ part13, uint32_t* __restrict__ H13){
  int b = blockIdx.x * blockDim.x + threadIdx.x;   // 8192 threads
  uint32_t s = 0;
  for (int p = 0; p < P13; p++) s += part13[(size_t)p * H13BINS + b];
  H13[b] = s;
}

// ---------------- single block: select candidate 13-bit bins ---------------
__global__ __launch_bounds__(1024) void k_sel13(const uint32_t* __restrict__ H13,
    uint32_t* __restrict__ ctl, uint8_t* __restrict__ table13,
    uint32_t k, uint32_t c, uint32_t n){
  __shared__ uint32_t sA[8192];
  __shared__ uint32_t sT[8192];
  __shared__ uint32_t sAbs[4096];
  __shared__ uint32_t cBin13[32], cRes[32];
  __shared__ uint32_t shv[4];   // 0:astar13 1:rrA 2:aboveA 3:nS
  int tid = threadIdx.x;

  // Phase A: abs selection at 13-bit level
  for (int a = tid; a < 4096; a += 1024) sAbs[a] = H13[4096 + a] + H13[4095 - a];
  __syncthreads();
  scan1(sAbs, sT, 4096);
  if (tid == 0){
    int astar = suf_search(sAbs, 4096, k - 1u);
    uint32_t aboveA = (astar + 1 < 4096) ? sAbs[astar + 1] : 0u;
    shv[0] = (uint32_t)astar; shv[1] = (k - 1u) - aboveA; shv[2] = aboveA;
  }
  __syncthreads();
  uint32_t astar13 = shv[0];

  // Phase B: signed suffix scan + 32 candidate ranks
  for (int i = tid; i < 8192; i += 1024) sA[i] = H13[i];
  __syncthreads();
  scan1(sA, sT, 8192);
  uint32_t posThr13 = 4096u + astar13;
  if (tid < 32){
    int i = tid & 15;
    uint32_t kr = (i < 8) ? (uint32_t)i * c : (uint32_t)(i - 7) * c - 1u;
    uint32_t Rr = (tid < 16) ? kr : (n - k + kr);
    int q = suf_search(sA, 8192, Rr);
    uint32_t aboveC = (q + 1 < 8192) ? sA[q + 1] : 0u;
    cBin13[tid] = (uint32_t)q;
    cRes[tid] = Rr - aboveC;
  }
  __syncthreads();

  if (tid == 0){
    uint32_t bins[NSLOT_MAX]; int nS = 0;
    bins[nS++] = posThr13;            // slot 0 = pos threshold 13-bin
    bins[nS++] = 4095u - astar13;     // slot 1 = neg threshold 13-bin
    for (int cd = 0; cd < 32; cd++){
      uint32_t b = cBin13[cd]; int s = -1;
      for (int t2 = 0; t2 < nS; t2++) if (bins[t2] == b){ s = t2; break; }
      if (s < 0){ s = nS; bins[nS++] = b; }
      ctl[CTL_C13SLOT + cd] = (uint32_t)s;
      ctl[CTL_C13RES + cd]  = cRes[cd];
    }
    for (int s = 0; s < nS; s++) ctl[CTL_S13BIN + s] = bins[s];
    ctl[CTL_NS13] = (uint32_t)nS;
    ctl[CTL_ASTAR13] = astar13;
    ctl[CTL_RRA] = shv[1];
    ctl[CTL_ABOVEA] = shv[2];
    ctl[CTL_POSAB13] = (posThr13 + 1u < 8192u) ? sA[posThr13 + 1] : 0u;
    shv[3] = (uint32_t)nS;
  }
  __syncthreads();
  // bin13 -> slot+1 lookup table (8192 bytes)
  for (int i = tid; i < 2048; i += 1024) ((uint32_t*)table13)[i] = 0u;
  __syncthreads();
  uint32_t nS = shv[3];
  if (tid < (int)nS) table13[ctl[CTL_S13BIN + tid]] = (uint8_t)(tid + 1);
}

// ---------------- pass 2: refine candidate bins to 22 bits (LDS) -----------
__global__ __launch_bounds__(1024) void k_hist9(const uint32_t* __restrict__ xb,
    const uint8_t* __restrict__ table13, const uint32_t* __restrict__ ctl,
    uint32_t* __restrict__ part9, int n4){
  __shared__ uint8_t tb[H13BINS];
  __shared__ uint32_t fine[NSLOT_MAX * 512];
  __shared__ uint32_t snS;
  int tid = threadIdx.x;
  for (int i = tid; i < 2048; i += 1024) ((uint32_t*)tb)[i] = ((const uint32_t*)table13)[i];
  if (tid == 0) snS = ctl[CTL_NS13];
  __syncthreads();
  int L = (int)snS * 512;
  for (int i = tid; i < L; i += 1024) fine[i] = 0u;
  __syncthreads();
  int stride = gridDim.x * blockDim.x;
  for (int i = blockIdx.x * blockDim.x + tid; i < n4; i += stride){
    uint4 v = ((const uint4*)xb)[i];
    uint32_t bv[4] = {v.x, v.y, v.z, v.w};
    #pragma unroll
    for (int j = 0; j < 4; j++){
      uint32_t key = skey(bv[j]);
      uint32_t s = tb[key >> 19];
      if (s) atomicAdd(&fine[(s - 1u) * 512u + ((key >> 10) & 511u)], 1u);
    }
  }
  __syncthreads();
  uint32_t* dst = part9 + (size_t)blockIdx.x * (NSLOT_MAX * 512);
  for (int i = tid; i < L; i += 1024) dst[i] = fine[i];
}

__global__ void k_red9(const uint32_t* __restrict__ part9,
    const uint32_t* __restrict__ ctl, uint32_t* __restrict__ H9){
  int L = (int)ctl[CTL_NS13] * 512;
  int b = blockIdx.x * blockDim.x + threadIdx.x;   // NSLOT_MAX*512 threads
  if (b >= L) return;
  uint32_t s = 0;
  for (int p = 0; p < P9; p++) s += part9[(size_t)p * (NSLOT_MAX * 512) + b];
  H9[b] = s;
}

// ---------------- single block: resolve 22-bit gather bins -----------------
__global__ __launch_bounds__(1024) void k_sel9(const uint32_t* __restrict__ H9,
    uint32_t* __restrict__ ctl){
  __shared__ uint32_t fine[GSL * 512];
  __shared__ uint32_t tmp[GSL * 512];
  __shared__ uint32_t absF[512], absT[512];
  __shared__ uint32_t s13bin[NSLOT_MAX];
  __shared__ uint32_t cSlot[32], cRes[32], cBin22[32], cRes2[32];
  __shared__ uint32_t sh[4];  // 0:jstar9 1:rr2 2:cntAbove 3:posAbove
  int tid = threadIdx.x;
  uint32_t nS = ctl[CTL_NS13];
  uint32_t astar13 = ctl[CTL_ASTAR13], rrA = ctl[CTL_RRA], aboveA = ctl[CTL_ABOVEA];
  if (tid < (int)NSLOT_MAX) s13bin[tid] = ctl[CTL_S13BIN + tid];
  if (tid < 32){ cSlot[tid] = ctl[CTL_C13SLOT + tid]; cRes[tid] = ctl[CTL_C13RES + tid]; }
  __syncthreads();

  for (uint32_t g0 = 0; g0 < nS; g0 += GSL){
    uint32_t gn = nS - g0; if (gn > GSL) gn = GSL;
    int L = (int)gn * 512;
    for (int i = tid; i < L; i += 1024) fine[i] = H9[g0 * 512u + (uint32_t)i];
    __syncthreads();
    if (g0 == 0){
      // abs refine from raw slot0/slot1 fine hists
      for (int j = tid; j < 512; j += 1024) absF[j] = fine[j] + fine[512 + 511 - j];
      __syncthreads();
      scan1(absF, absT, 512);
      if (tid == 0){
        int j = suf_search(absF, 512, rrA);
        uint32_t ab9 = (j + 1 < 512) ? absF[j + 1] : 0u;
        sh[0] = (uint32_t)j; sh[1] = rrA - ab9; sh[2] = aboveA + ab9;
      }
      __syncthreads();
    }
    scan_seg512(fine, tmp, L);
    if (g0 == 0 && tid == 0){
      uint32_t j = sh[0];
      uint32_t pfa = (j + 1u < 512u) ? fine[j + 1u] : 0u;   // slot0 suffix above jstar9
      sh[3] = ctl[CTL_POSAB13] + pfa;
    }
    if (tid < 32){
      uint32_t s = cSlot[tid];
      if (s >= g0 && s < g0 + gn){
        uint32_t* seg = fine + (s - g0) * 512u;
        int bl = suf_search(seg, 512, cRes[tid]);
        uint32_t ab = (bl + 1 < 512) ? seg[bl + 1] : 0u;
        cBin22[tid] = (s13bin[s] << 9) | (uint32_t)bl;
        cRes2[tid] = cRes[tid] - ab;
      }
    }
    __syncthreads();
  }

  if (tid == 0){
    uint32_t jstar9 = sh[0];
    uint32_t posBin22 = ((4096u + astar13) << 9) | jstar9;
    uint32_t negBin22 = ((4095u - astar13) << 9) | (511u - jstar9);
    uint32_t bins[NSLOT_MAX]; int nG = 0;
    bins[nG++] = posBin22;
    bins[nG++] = negBin22;
    for (int cd = 0; cd < 32; cd++){
      uint32_t b = cBin22[cd]; int s = -1;
      for (int t2 = 0; t2 < nG; t2++) if (bins[t2] == b){ s = t2; break; }
      if (s < 0){ s = nG; bins[nG++] = b; }
      ctl[CTL_CANDSLOT + cd] = (uint32_t)s;
      ctl[CTL_CANDRES + cd]  = cRes2[cd];
    }
    ctl[CTL_NSLOT] = (uint32_t)nG;
    for (int s = 0; s < nG; s++) ctl[CTL_SLOTBIN + s] = bins[s];
    ctl[CTL_RR2] = sh[1];
    ctl[CTL_CNTABOVE] = sh[2];
    ctl[CTL_POSABOVE] = sh[3];
    ctl[CTL_A21] = (astar13 << 9) | jstar9;
  }
}

// ---------------- pass 3: gather via 22-bit LDS hash table -----------------
__global__ __launch_bounds__(256) void k_gather(const uint32_t* __restrict__ xb,
    const uint32_t* __restrict__ ctl, uint32_t* __restrict__ slotCnt,
    uint64_t* __restrict__ slotBuf, int n4){
  __shared__ uint32_t htab[4096];     // entry = (bin22<<8)|(slot+1), 0 = empty
  __shared__ uint32_t lcnt[NSLOT_MAX];
  __shared__ uint32_t lbase[NSLOT_MAX];
  int tid = threadIdx.x;
  for (int i = tid; i < 4096; i += 256) htab[i] = 0u;
  __syncthreads();
  if (tid == 0){
    uint32_t nS = ctl[CTL_NSLOT];
    for (uint32_t s = 0; s < nS; s++){
      uint32_t b = ctl[CTL_SLOTBIN + s];
      uint32_t h = (b * 2654435761u) >> 20;
      while (htab[h]) h = (h + 1u) & 4095u;
      htab[h] = (b << 8) | (s + 1u);
    }
  }
  __syncthreads();

  int stride = gridDim.x * blockDim.x;
  int iters = (n4 + stride - 1) / stride;
  for (int it = 0; it < iters; it++){
    int i = blockIdx.x * blockDim.x + tid + it * stride;
    if (tid < NSLOT_MAX) lcnt[tid] = 0u;
    __syncthreads();
    int nh = 0;
    uint32_t hsp[4];   // (slot<<16)|pos  (pos < 1024 within block)
    uint32_t hkey[4], hidx[4];
    if (i < n4){
      uint4 v = ((const uint4*)xb)[i];
      uint32_t bv[4] = {v.x, v.y, v.z, v.w};
      uint32_t base = (uint32_t)i * 4u;
      #pragma unroll
      for (int j = 0; j < 4; j++){
        uint32_t key = skey(bv[j]);
        uint32_t bin = key >> 10;
        uint32_t h = (bin * 2654435761u) >> 20;
        while (true){
          uint32_t e = htab[h];
          if (!e) break;
          if ((e >> 8) == bin){
            uint32_t s = (e & 255u) - 1u;
            uint32_t p = atomicAdd(&lcnt[s], 1u);
            hsp[nh] = (s << 16) | p; hkey[nh] = key; hidx[nh] = base + (uint32_t)j;
            nh++;
            break;
          }
          h = (h + 1u) & 4095u;
        }
      }
    }
    __syncthreads();
    if (tid < NSLOT_MAX){
      uint32_t cc = lcnt[tid];
      lbase[tid] = cc ? atomicAdd(&slotCnt[tid], cc) : 0u;
    }
    __syncthreads();
    for (int e = 0; e < nh; e++){
      uint32_t s = hsp[e] >> 16;
      uint32_t pos = lbase[s] + (hsp[e] & 0xFFFFu);
      if (pos < SLOT_CAP)
        slotBuf[(size_t)s * SLOT_CAP + pos] = ((uint64_t)hkey[e] << 32) | (uint64_t)hidx[e];
    }
    __syncthreads();
  }
}

// ---------------- single block: exact t, ties, num_pos, boundaries ---------
__global__ __launch_bounds__(1024) void k_s2(uint32_t* __restrict__ ctl,
    const uint32_t* __restrict__ slotCnt, const uint64_t* __restrict__ slotBuf,
    uint32_t k, uint32_t c){
  __shared__ uint32_t sH[1024];
  __shared__ uint32_t sS[1024];
  __shared__ uint32_t sT[1024];
  __shared__ uint32_t red[1024];
  __shared__ uint32_t tieIdx[MAX_TIES];
  __shared__ uint8_t  tieSgn[MAX_TIES];
  __shared__ uint32_t sCnt[4];
  __shared__ float    tv[16];
  int tid = threadIdx.x;
  uint32_t a21 = ctl[CTL_A21], rr2 = ctl[CTL_RR2], cntAbove = ctl[CTL_CNTABOVE];
  uint32_t cntP = slotCnt[0]; if (cntP > SLOT_CAP) cntP = SLOT_CAP;
  uint32_t cntN = slotCnt[1]; if (cntN > SLOT_CAP) cntN = SLOT_CAP;

  // resolve low 10 bits of |t|
  for (int j = tid; j < 1024; j += 1024) sH[j] = 0u;
  __syncthreads();
  for (uint32_t e = tid; e < cntP; e += 1024){
    uint32_t key = (uint32_t)(slotBuf[e] >> 32);
    atomicAdd(&sH[key & 1023u], 1u);
  }
  for (uint32_t e = tid; e < cntN; e += 1024){
    uint32_t key = (uint32_t)(slotBuf[SLOT_CAP + e] >> 32);
    uint32_t m = 0x7FFFFFFFu - key;
    atomicAdd(&sH[m & 1023u], 1u);
  }
  __syncthreads();
  for (int j = tid; j < 1024; j += 1024) sS[j] = sH[j];
  __syncthreads();
  scan1(sS, sT, 1024);
  int l = suf_search(sS, 1024, rr2);
  uint32_t w = (l + 1 < 1024) ? sS[l + 1] : 0u;
  uint32_t cnt_gt = cntAbove + w;
  uint32_t r_ties = k - cnt_gt;
  uint32_t t_key = (a21 << 10) | (uint32_t)l;

  // collect ties, keep r_ties smallest flat indices (stable, as jax top_k)
  if (tid == 0){ sCnt[0] = 0u; sCnt[1] = 0u; sCnt[2] = 0u; }
  __syncthreads();
  for (uint32_t e = tid; e < cntP; e += 1024){
    uint64_t ent = slotBuf[e];
    uint32_t key = (uint32_t)(ent >> 32);
    if ((key & 1023u) == (uint32_t)l){
      uint32_t p = atomicAdd(&sCnt[0], 1u);
      if (p < MAX_TIES){ tieIdx[p] = (uint32_t)ent; tieSgn[p] = 1; }
    }
  }
  for (uint32_t e = tid; e < cntN; e += 1024){
    uint64_t ent = slotBuf[SLOT_CAP + e];
    uint32_t key = (uint32_t)(ent >> 32);
    uint32_t m = 0x7FFFFFFFu - key;
    if ((m & 1023u) == (uint32_t)l){
      uint32_t p = atomicAdd(&sCnt[0], 1u);
      if (p < MAX_TIES){ tieIdx[p] = (uint32_t)ent; tieSgn[p] = 0; }
    }
  }
  __syncthreads();
  uint32_t mT = sCnt[0]; if (mT > MAX_TIES) mT = MAX_TIES;
  for (uint32_t e = tid; e < mT; e += 1024){
    uint32_t my = tieIdx[e];
    uint32_t rank = 0;
    for (uint32_t f = 0; f < mT; f++) rank += (tieIdx[f] < my) ? 1u : 0u;
    if (rank < r_ties){
      uint32_t p = atomicAdd(&sCnt[1], 1u);
      if (p < MAX_TIES) ctl[CTL_TIEIDX + p] = my;
      if (tieSgn[e]) atomicAdd(&sCnt[2], 1u);
    }
  }
  __syncthreads();
  uint32_t nSel = sCnt[1]; if (nSel > MAX_TIES) nSel = MAX_TIES;
  uint32_t selPos = sCnt[2];

  // num_pos = #{x > |t|} + selected positive ties
  uint32_t part = 0;
  for (uint32_t e = tid; e < cntP; e += 1024){
    uint32_t key = (uint32_t)(slotBuf[e] >> 32);
    if ((key & 1023u) > (uint32_t)l) part++;
  }
  red[tid] = part;
  __syncthreads();
  for (int o = 512; o; o >>= 1){ if (tid < o) red[tid] += red[tid + o]; __syncthreads(); }
  uint32_t num_pos = red[0] + ctl[CTL_POSABOVE] + selPos;
  __syncthreads();

  // resolve the 16 boundary values (mx_p = kept rank p*c, mn_p = (p+1)*c-1)
  for (int i = 0; i < 16; i++){
    uint32_t kr = (i < 8) ? (uint32_t)i * c : (uint32_t)(i - 7) * c - 1u;
    int cand = (kr < num_pos) ? i : (16 + i);
    uint32_t slot  = ctl[CTL_CANDSLOT + cand];
    uint32_t resid = ctl[CTL_CANDRES + cand];
    uint32_t bin   = ctl[CTL_SLOTBIN + slot];
    uint32_t cnt2  = slotCnt[slot]; if (cnt2 > SLOT_CAP) cnt2 = SLOT_CAP;
    __syncthreads();
    for (int j = tid; j < 1024; j += 1024) sH[j] = 0u;
    __syncthreads();
    for (uint32_t e = tid; e < cnt2; e += 1024){
      uint32_t key = (uint32_t)(slotBuf[(size_t)slot * SLOT_CAP + e] >> 32);
      atomicAdd(&sH[key & 1023u], 1u);
    }
    __syncthreads();
    scan1(sH, sT, 1024);
    int bl = suf_search(sH, 1024, resid);
    uint32_t fullkey = (bin << 10) | (uint32_t)bl;
    uint32_t bits = (fullkey & 0x80000000u) ? (fullkey ^ 0x80000000u) : ~fullkey;
    if (tid == 0) tv[i] = __uint_as_float(bits);
    __syncthreads();
  }

  if (tid == 0){
    ctl[CTL_TKEY] = t_key;
    ctl[CTL_NTIES] = nSel;
    for (int j = 1; j < 8; j++) ctl[CTL_BND + (j - 1)] = __float_as_uint(tv[j]);
    for (int p = 0; p < 8; p++){
      float mx = tv[p], mn = tv[8 + p];
      ctl[CTL_MN + p] = __float_as_uint(mn);
      ctl[CTL_MX + p] = __float_as_uint(mx);
      ctl[CTL_STEP + p] = __float_as_uint((mx - mn) / 255.0f);
    }
  }
}

// ---------------- pass 4: write quantized output ---------------------------
__global__ void k_out(const uint32_t* __restrict__ xb, float* __restrict__ out,
    const uint32_t* __restrict__ ctl, int n4){
  __shared__ float sB[7], sMn[8], sMx[8], sSt[8];
  __shared__ uint32_t sTK, sNT;
  __shared__ uint32_t sTie[MAX_TIES];
  int tid = threadIdx.x;
  if (tid == 0){ sTK = ctl[CTL_TKEY]; sNT = ctl[CTL_NTIES]; }
  if (tid < 7) sB[tid] = __uint_as_float(ctl[CTL_BND + tid]);
  if (tid < 8){
    sMn[tid] = __uint_as_float(ctl[CTL_MN + tid]);
    sMx[tid] = __uint_as_float(ctl[CTL_MX + tid]);
    sSt[tid] = __uint_as_float(ctl[CTL_STEP + tid]);
  }
  __syncthreads();
  uint32_t nt = sNT, tk = sTK;
  for (int e = tid; e < (int)nt; e += blockDim.x) sTie[e] = ctl[CTL_TIEIDX + e];
  __syncthreads();
  int i = blockIdx.x * blockDim.x + tid;
  if (i >= n4) return;
  uint4 v = ((const uint4*)xb)[i];
  uint32_t bv[4] = {v.x, v.y, v.z, v.w};
  float ov[4];
  uint32_t base = (uint32_t)i * 4u;
  #pragma unroll
  for (int j = 0; j < 4; j++){
    uint32_t b = bv[j];
    uint32_t m = b & 0x7FFFFFFFu;
    float q = 0.0f;
    bool keep = m > tk;
    if (m == tk){
      uint32_t idx = base + (uint32_t)j;
      for (uint32_t e = 0; e < nt; e++) if (sTie[e] == idx){ keep = true; break; }
    }
    if (keep){
      float x = __uint_as_float(b);
      int p = 0;
      #pragma unroll
      for (int j2 = 0; j2 < 7; j2++) p += (sB[j2] >= x) ? 1 : 0;
      float mn = sMn[p], mx = sMx[p], st = sSt[p];
      if (mn == mx) q = x;
      else {
        float sst = (st == 0.0f) ? 1.0f : st;
        q = rintf((x - mn) / sst) * st + mn;
      }
    }
    ov[j] = q;
  }
  ((float4*)out)[i] = make_float4(ov[0], ov[1], ov[2], ov[3]);
}

// ---------------------------------------------------------------------------
extern "C" void kernel_launch(void* const* d_in, const int* in_sizes, int n_in,
                              void* d_out, int out_size, void* d_ws, size_t ws_size,
                              hipStream_t stream){
  const uint32_t* xb = (const uint32_t*)d_in[0];
  float* out = (float*)d_out;
  uint32_t n = (uint32_t)in_sizes[0];
  uint32_t k = n / 4u;
  uint32_t c = k / 8u;

  // ws layout (u32 units)
  uint32_t* w = (uint32_t*)d_ws;
  uint32_t* H13     = w;                            // 8192
  uint32_t* H9      = H13 + H13BINS;                // 40*512 = 20480
  uint8_t*  table13 = (uint8_t*)(H9 + NSLOT_MAX*512); // 8192 B (2048 u32)
  uint32_t* ctl     = (uint32_t*)(table13 + H13BINS); // 1280
  uint32_t* slotCnt = ctl + CTL_SIZE;               // 40
  uint64_t* slotBuf = (uint64_t*)(slotCnt + NSLOT_MAX); // 40*8192 u64
  uint32_t* part13  = (uint32_t*)(slotBuf + (size_t)NSLOT_MAX * SLOT_CAP);
  uint32_t* part9   = part13 + (size_t)P13 * H13BINS;
  size_t endu32 = (size_t)((uint32_t*)part9 - w) + (size_t)P9 * NSLOT_MAX * 512;
  if (ws_size < endu32 * 4u){
    hipMemsetAsync(d_out, 0, (size_t)out_size * 4u, stream);
    return;
  }
  // zero ctl + slotCnt (contiguous)
  hipMemsetAsync(ctl, 0, (size_t)(CTL_SIZE + NSLOT_MAX) * 4u, stream);

  int n4 = (int)(n / 4u);
  int blocksE = (n4 + 255) / 256;
  k_hist13<<<P13, 1024, 0, stream>>>(xb, part13, n4);
  k_red13 <<<H13BINS / 256, 256, 0, stream>>>(part13, H13);
  k_sel13 <<<1, 1024, 0, stream>>>(H13, ctl, table13, k, c, n);
  k_hist9 <<<P9, 1024, 0, stream>>>(xb, table13, ctl, part9, n4);
  k_red9  <<<(NSLOT_MAX * 512) / 256, 256, 0, stream>>>(part9, ctl, H9);
  k_sel9  <<<1, 1024, 0, stream>>>(H9, ctl);
  k_gather<<<GATHER_BLOCKS, 256, 0, stream>>>(xb, ctl, slotCnt, slotBuf, n4);
  k_s2    <<<1, 1024, 0, stream>>>(ctl, slotCnt, slotBuf, k, c);
  k_out   <<<blocksE, 256, 0, stream>>>(xb, out, ctl, n4);
}

// Round 4
// 563.311 us; speedup vs baseline: 4.0465x; 1.0977x over previous
//
#include <hip/hip_runtime.h>
#include <stdint.h>

// ---------------------------------------------------------------------------
// TopkQuantLayer: out = scatter(quant(top 25% by |x|)), n = 32M fp32.
// R3: barrier-free k_gather (hash table prebuilt in k_sel9, direct global
// atomics — R3's barrier-per-iteration structure was latency-bound at 1.1
// TB/s effective); k_s2 boundary resolution parallelized across 16 waves
// (private LDS hists + shfl suffix scan) replacing 16 sequential 1024-scans;
// memset dispatch folded into k_sel9; hist kernels 2x unrolled for MLP.
// ---------------------------------------------------------------------------

#define H13BINS   8192
#define P13       256      // hist13 grid (partial count)
#define P9        256      // hist9 grid
#define NSLOT_MAX 40
#define SLOT_CAP  8192
#define MAX_TIES  1024
#define GSL       16       // slots per scan-group in k_sel9
#define HTAB_SZ   2048
#define GATHER_BLOCKS 8192

// ctl word offsets
#define CTL_ASTAR13   0
#define CTL_RRA       1
#define CTL_ABOVEA    2
#define CTL_NS13      3
#define CTL_POSAB13   4
#define CTL_TKEY      5
#define CTL_NTIES     6
#define CTL_RR2       7
#define CTL_CNTABOVE  8
#define CTL_POSABOVE  9
#define CTL_NSLOT     10
#define CTL_A21       11
#define CTL_S13BIN    16   // 40
#define CTL_C13SLOT   56   // 32
#define CTL_C13RES    88   // 32
#define CTL_SLOTBIN   120  // 40 (gather bin22 list)
#define CTL_CANDSLOT  160  // 32
#define CTL_CANDRES   192  // 32
#define CTL_BND       224  // 7
#define CTL_MN        232  // 8
#define CTL_MX        240  // 8
#define CTL_STEP      248  // 8
#define CTL_TIEIDX    256  // 1024
#define CTL_SIZE      1280

__device__ __forceinline__ uint32_t skey(uint32_t b){
  return (b & 0x80000000u) ? ~b : (b | 0x80000000u);   // ascending-sortable
}

// inclusive suffix scan, one segment of width L (L<=8192), block-wide Hillis
__device__ void scan1(uint32_t* a, uint32_t* tmp, int L){
  for (int d = 1; d < L; d <<= 1){
    for (int i = threadIdx.x; i < L; i += blockDim.x)
      tmp[i] = a[i] + ((i + d < L) ? a[i + d] : 0u);
    __syncthreads();
    for (int i = threadIdx.x; i < L; i += blockDim.x) a[i] = tmp[i];
    __syncthreads();
  }
}

// segmented inclusive suffix scan: segments of width 512
__device__ void scan_seg512(uint32_t* a, uint32_t* tmp, int total){
  for (int d = 1; d < 512; d <<= 1){
    for (int i = threadIdx.x; i < total; i += blockDim.x){
      int j = i & 511;
      tmp[i] = a[i] + ((j + d < 512) ? a[i + d] : 0u);
    }
    __syncthreads();
    for (int i = threadIdx.x; i < total; i += blockDim.x) a[i] = tmp[i];
    __syncthreads();
  }
}

// lo = max{ i : suf[i] > R } (virtual suf[L]=0); requires suf[0] > R
__device__ int suf_search(const uint32_t* suf, int L, uint32_t R){
  int lo = 0, hi = L;
  while (hi - lo > 1){
    int mid = (lo + hi) >> 1;
    uint32_t s = (mid < L) ? suf[mid] : 0u;
    if (s > R) lo = mid; else hi = mid;
  }
  return lo;
}

// ---------------- pass 1: coarse 13-bit histogram (LDS, partials) ----------
__global__ __launch_bounds__(1024) void k_hist13(const uint32_t* __restrict__ xb,
    uint32_t* __restrict__ part13, int n4){
  __shared__ uint32_t h[H13BINS];
  int tid = threadIdx.x;
  for (int i = tid; i < H13BINS; i += 1024) h[i] = 0u;
  __syncthreads();
  int stride = gridDim.x * blockDim.x;
  int i = blockIdx.x * blockDim.x + tid;
  for (; i + stride < n4; i += 2 * stride){
    uint4 a = ((const uint4*)xb)[i];
    uint4 b = ((const uint4*)xb)[i + stride];
    atomicAdd(&h[skey(a.x) >> 19], 1u);
    atomicAdd(&h[skey(a.y) >> 19], 1u);
    atomicAdd(&h[skey(a.z) >> 19], 1u);
    atomicAdd(&h[skey(a.w) >> 19], 1u);
    atomicAdd(&h[skey(b.x) >> 19], 1u);
    atomicAdd(&h[skey(b.y) >> 19], 1u);
    atomicAdd(&h[skey(b.z) >> 19], 1u);
    atomicAdd(&h[skey(b.w) >> 19], 1u);
  }
  if (i < n4){
    uint4 a = ((const uint4*)xb)[i];
    atomicAdd(&h[skey(a.x) >> 19], 1u);
    atomicAdd(&h[skey(a.y) >> 19], 1u);
    atomicAdd(&h[skey(a.z) >> 19], 1u);
    atomicAdd(&h[skey(a.w) >> 19], 1u);
  }
  __syncthreads();
  uint32_t* dst = part13 + (size_t)blockIdx.x * H13BINS;
  for (int j = tid; j < H13BINS; j += 1024) dst[j] = h[j];
}

__global__ void k_red13(const uint32_t* __restrict__ part13, uint32_t* __restrict__ H13){
  int b = blockIdx.x * blockDim.x + threadIdx.x;   // 8192 threads
  uint32_t s = 0;
  for (int p = 0; p < P13; p++) s += part13[(size_t)p * H13BINS + b];
  H13[b] = s;
}

// ---------------- single block: select candidate 13-bit bins ---------------
__global__ __launch_bounds__(1024) void k_sel13(const uint32_t* __restrict__ H13,
    uint32_t* __restrict__ ctl, uint8_t* __restrict__ table13,
    uint32_t k, uint32_t c, uint32_t n){
  __shared__ uint32_t sA[8192];
  __shared__ uint32_t sT[8192];
  __shared__ uint32_t sAbs[4096];
  __shared__ uint32_t cBin13[32], cRes[32];
  __shared__ uint32_t shv[4];   // 0:astar13 1:rrA 2:aboveA 3:nS
  int tid = threadIdx.x;

  // Phase A: abs selection at 13-bit level
  for (int a = tid; a < 4096; a += 1024) sAbs[a] = H13[4096 + a] + H13[4095 - a];
  __syncthreads();
  scan1(sAbs, sT, 4096);
  if (tid == 0){
    int astar = suf_search(sAbs, 4096, k - 1u);
    uint32_t aboveA = (astar + 1 < 4096) ? sAbs[astar + 1] : 0u;
    shv[0] = (uint32_t)astar; shv[1] = (k - 1u) - aboveA; shv[2] = aboveA;
  }
  __syncthreads();
  uint32_t astar13 = shv[0];

  // Phase B: signed suffix scan + 32 candidate ranks
  for (int i = tid; i < 8192; i += 1024) sA[i] = H13[i];
  __syncthreads();
  scan1(sA, sT, 8192);
  uint32_t posThr13 = 4096u + astar13;
  if (tid < 32){
    int i = tid & 15;
    uint32_t kr = (i < 8) ? (uint32_t)i * c : (uint32_t)(i - 7) * c - 1u;
    uint32_t Rr = (tid < 16) ? kr : (n - k + kr);
    int q = suf_search(sA, 8192, Rr);
    uint32_t aboveC = (q + 1 < 8192) ? sA[q + 1] : 0u;
    cBin13[tid] = (uint32_t)q;
    cRes[tid] = Rr - aboveC;
  }
  __syncthreads();

  if (tid == 0){
    uint32_t bins[NSLOT_MAX]; int nS = 0;
    bins[nS++] = posThr13;            // slot 0 = pos threshold 13-bin
    bins[nS++] = 4095u - astar13;     // slot 1 = neg threshold 13-bin
    for (int cd = 0; cd < 32; cd++){
      uint32_t b = cBin13[cd]; int s = -1;
      for (int t2 = 0; t2 < nS; t2++) if (bins[t2] == b){ s = t2; break; }
      if (s < 0){ s = nS; bins[nS++] = b; }
      ctl[CTL_C13SLOT + cd] = (uint32_t)s;
      ctl[CTL_C13RES + cd]  = cRes[cd];
    }
    for (int s = 0; s < nS; s++) ctl[CTL_S13BIN + s] = bins[s];
    ctl[CTL_NS13] = (uint32_t)nS;
    ctl[CTL_ASTAR13] = astar13;
    ctl[CTL_RRA] = shv[1];
    ctl[CTL_ABOVEA] = shv[2];
    ctl[CTL_POSAB13] = (posThr13 + 1u < 8192u) ? sA[posThr13 + 1] : 0u;
    shv[3] = (uint32_t)nS;
  }
  __syncthreads();
  // bin13 -> slot+1 lookup table (8192 bytes)
  for (int i = tid; i < 2048; i += 1024) ((uint32_t*)table13)[i] = 0u;
  __syncthreads();
  uint32_t nS = shv[3];
  if (tid < (int)nS) table13[ctl[CTL_S13BIN + tid]] = (uint8_t)(tid + 1);
}

// ---------------- pass 2: refine candidate bins to 22 bits (LDS) -----------
__global__ __launch_bounds__(1024) void k_hist9(const uint32_t* __restrict__ xb,
    const uint8_t* __restrict__ table13, const uint32_t* __restrict__ ctl,
    uint32_t* __restrict__ part9, int n4){
  __shared__ uint8_t tb[H13BINS];
  __shared__ uint32_t fine[NSLOT_MAX * 512];
  __shared__ uint32_t snS;
  int tid = threadIdx.x;
  for (int i = tid; i < 2048; i += 1024) ((uint32_t*)tb)[i] = ((const uint32_t*)table13)[i];
  if (tid == 0) snS = ctl[CTL_NS13];
  __syncthreads();
  int L = (int)snS * 512;
  for (int i = tid; i < L; i += 1024) fine[i] = 0u;
  __syncthreads();
  int stride = gridDim.x * blockDim.x;
  int i = blockIdx.x * blockDim.x + tid;
  for (; i + stride < n4; i += 2 * stride){
    uint4 a = ((const uint4*)xb)[i];
    uint4 b = ((const uint4*)xb)[i + stride];
    uint32_t bv[8] = {a.x, a.y, a.z, a.w, b.x, b.y, b.z, b.w};
    #pragma unroll
    for (int j = 0; j < 8; j++){
      uint32_t key = skey(bv[j]);
      uint32_t s = tb[key >> 19];
      if (s) atomicAdd(&fine[(s - 1u) * 512u + ((key >> 10) & 511u)], 1u);
    }
  }
  if (i < n4){
    uint4 a = ((const uint4*)xb)[i];
    uint32_t bv[4] = {a.x, a.y, a.z, a.w};
    #pragma unroll
    for (int j = 0; j < 4; j++){
      uint32_t key = skey(bv[j]);
      uint32_t s = tb[key >> 19];
      if (s) atomicAdd(&fine[(s - 1u) * 512u + ((key >> 10) & 511u)], 1u);
    }
  }
  __syncthreads();
  uint32_t* dst = part9 + (size_t)blockIdx.x * (NSLOT_MAX * 512);
  for (int j = tid; j < L; j += 1024) dst[j] = fine[j];
}

__global__ void k_red9(const uint32_t* __restrict__ part9,
    const uint32_t* __restrict__ ctl, uint32_t* __restrict__ H9){
  int L = (int)ctl[CTL_NS13] * 512;
  int b = blockIdx.x * blockDim.x + threadIdx.x;   // NSLOT_MAX*512 threads
  if (b >= L) return;
  uint32_t s = 0;
  for (int p = 0; p < P9; p++) s += part9[(size_t)p * (NSLOT_MAX * 512) + b];
  H9[b] = s;
}

// ---------------- single block: resolve 22-bit gather bins + hash table ----
__global__ __launch_bounds__(1024) void k_sel9(const uint32_t* __restrict__ H9,
    uint32_t* __restrict__ ctl, uint32_t* __restrict__ htabG,
    uint32_t* __restrict__ slotCnt){
  __shared__ uint32_t fine[GSL * 512];
  __shared__ uint32_t tmp[GSL * 512];
  __shared__ uint32_t absF[512], absT[512];
  __shared__ uint32_t s13bin[NSLOT_MAX];
  __shared__ uint32_t cSlot[32], cRes[32], cBin22[32], cRes2[32];
  __shared__ uint32_t htabS[HTAB_SZ];
  __shared__ uint32_t sh[4];  // 0:jstar9 1:rr2 2:cntAbove 3:posAbove
  int tid = threadIdx.x;
  uint32_t nS = ctl[CTL_NS13];
  uint32_t astar13 = ctl[CTL_ASTAR13], rrA = ctl[CTL_RRA], aboveA = ctl[CTL_ABOVEA];
  if (tid < (int)NSLOT_MAX) s13bin[tid] = ctl[CTL_S13BIN + tid];
  if (tid < 32){ cSlot[tid] = ctl[CTL_C13SLOT + tid]; cRes[tid] = ctl[CTL_C13RES + tid]; }
  for (int i = tid; i < HTAB_SZ; i += 1024) htabS[i] = 0u;
  __syncthreads();

  for (uint32_t g0 = 0; g0 < nS; g0 += GSL){
    uint32_t gn = nS - g0; if (gn > GSL) gn = GSL;
    int L = (int)gn * 512;
    for (int i = tid; i < L; i += 1024) fine[i] = H9[g0 * 512u + (uint32_t)i];
    __syncthreads();
    if (g0 == 0){
      // abs refine from raw slot0/slot1 fine hists
      for (int j = tid; j < 512; j += 1024) absF[j] = fine[j] + fine[512 + 511 - j];
      __syncthreads();
      scan1(absF, absT, 512);
      if (tid == 0){
        int j = suf_search(absF, 512, rrA);
        uint32_t ab9 = (j + 1 < 512) ? absF[j + 1] : 0u;
        sh[0] = (uint32_t)j; sh[1] = rrA - ab9; sh[2] = aboveA + ab9;
      }
      __syncthreads();
    }
    scan_seg512(fine, tmp, L);
    if (g0 == 0 && tid == 0){
      uint32_t j = sh[0];
      uint32_t pfa = (j + 1u < 512u) ? fine[j + 1u] : 0u;   // slot0 suffix above jstar9
      sh[3] = ctl[CTL_POSAB13] + pfa;
    }
    if (tid < 32){
      uint32_t s = cSlot[tid];
      if (s >= g0 && s < g0 + gn){
        uint32_t* seg = fine + (s - g0) * 512u;
        int bl = suf_search(seg, 512, cRes[tid]);
        uint32_t ab = (bl + 1 < 512) ? seg[bl + 1] : 0u;
        cBin22[tid] = (s13bin[s] << 9) | (uint32_t)bl;
        cRes2[tid] = cRes[tid] - ab;
      }
    }
    __syncthreads();
  }

  if (tid == 0){
    uint32_t jstar9 = sh[0];
    uint32_t posBin22 = ((4096u + astar13) << 9) | jstar9;
    uint32_t negBin22 = ((4095u - astar13) << 9) | (511u - jstar9);
    uint32_t bins[NSLOT_MAX]; int nG = 0;
    bins[nG++] = posBin22;
    bins[nG++] = negBin22;
    for (int cd = 0; cd < 32; cd++){
      uint32_t b = cBin22[cd]; int s = -1;
      for (int t2 = 0; t2 < nG; t2++) if (bins[t2] == b){ s = t2; break; }
      if (s < 0){ s = nG; bins[nG++] = b; }
      ctl[CTL_CANDSLOT + cd] = (uint32_t)s;
      ctl[CTL_CANDRES + cd]  = cRes2[cd];
    }
    ctl[CTL_NSLOT] = (uint32_t)nG;
    for (int s = 0; s < nG; s++) ctl[CTL_SLOTBIN + s] = bins[s];
    ctl[CTL_RR2] = sh[1];
    ctl[CTL_CNTABOVE] = sh[2];
    ctl[CTL_POSABOVE] = sh[3];
    ctl[CTL_A21] = (astar13 << 9) | jstar9;
    // build gather hash table: entry = (bin22<<8)|(slot+1), 0 = empty
    for (int s = 0; s < nG; s++){
      uint32_t b = bins[s];
      uint32_t h = (b * 2654435761u) >> 21;
      while (htabS[h]) h = (h + 1u) & (HTAB_SZ - 1u);
      htabS[h] = (b << 8) | (uint32_t)(s + 1);
    }
  }
  __syncthreads();
  for (int i = tid; i < HTAB_SZ; i += 1024) htabG[i] = htabS[i];
  if (tid < NSLOT_MAX) slotCnt[tid] = 0u;   // replaces host-side memset
}

// ---------------- pass 3: barrier-free gather via LDS hash table -----------
__global__ __launch_bounds__(256) void k_gather(const uint32_t* __restrict__ xb,
    const uint32_t* __restrict__ htabG, uint32_t* __restrict__ slotCnt,
    uint64_t* __restrict__ slotBuf, int n4){
  __shared__ uint32_t htab[HTAB_SZ];
  int tid = threadIdx.x;
  for (int i = tid; i < HTAB_SZ; i += 256) htab[i] = htabG[i];
  __syncthreads();
  int stride = gridDim.x * blockDim.x;
  for (int i = blockIdx.x * blockDim.x + tid; i < n4; i += stride){
    uint4 v = ((const uint4*)xb)[i];
    uint32_t bv[4] = {v.x, v.y, v.z, v.w};
    uint32_t base = (uint32_t)i * 4u;
    #pragma unroll
    for (int j = 0; j < 4; j++){
      uint32_t key = skey(bv[j]);
      uint32_t bin = key >> 10;
      uint32_t h = (bin * 2654435761u) >> 21;
      while (true){
        uint32_t e = htab[h];
        if (!e) break;
        if ((e >> 8) == bin){
          uint32_t s = (e & 255u) - 1u;
          uint32_t pos = atomicAdd(&slotCnt[s], 1u);
          if (pos < SLOT_CAP)
            slotBuf[(size_t)s * SLOT_CAP + pos] = ((uint64_t)key << 32) | (uint64_t)(base + (uint32_t)j);
          break;
        }
        h = (h + 1u) & (HTAB_SZ - 1u);
      }
    }
  }
}

// ---------------- single block: exact t, ties, num_pos, boundaries ---------
__global__ __launch_bounds__(1024) void k_s2(uint32_t* __restrict__ ctl,
    const uint32_t* __restrict__ slotCnt, const uint64_t* __restrict__ slotBuf,
    uint32_t k, uint32_t c){
  __shared__ uint32_t sH[1024];
  __shared__ uint32_t sS[1024];
  __shared__ uint32_t sT[1024];
  __shared__ uint32_t red[1024];
  __shared__ uint32_t bHist[16 * 1024];     // per-wave boundary histograms
  __shared__ uint32_t tieIdx[MAX_TIES];
  __shared__ uint8_t  tieSgn[MAX_TIES];
  __shared__ uint32_t sCnt[4];
  __shared__ uint32_t tvU[16];
  int tid = threadIdx.x;
  uint32_t a21 = ctl[CTL_A21], rr2 = ctl[CTL_RR2], cntAbove = ctl[CTL_CNTABOVE];
  uint32_t cntP = slotCnt[0]; if (cntP > SLOT_CAP) cntP = SLOT_CAP;
  uint32_t cntN = slotCnt[1]; if (cntN > SLOT_CAP) cntN = SLOT_CAP;

  // resolve low 10 bits of |t|
  for (int j = tid; j < 1024; j += 1024) sH[j] = 0u;
  __syncthreads();
  for (uint32_t e = tid; e < cntP; e += 1024){
    uint32_t key = (uint32_t)(slotBuf[e] >> 32);
    atomicAdd(&sH[key & 1023u], 1u);
  }
  for (uint32_t e = tid; e < cntN; e += 1024){
    uint32_t key = (uint32_t)(slotBuf[SLOT_CAP + e] >> 32);
    uint32_t m = 0x7FFFFFFFu - key;
    atomicAdd(&sH[m & 1023u], 1u);
  }
  __syncthreads();
  for (int j = tid; j < 1024; j += 1024) sS[j] = sH[j];
  __syncthreads();
  scan1(sS, sT, 1024);
  int l = suf_search(sS, 1024, rr2);
  uint32_t w = (l + 1 < 1024) ? sS[l + 1] : 0u;
  uint32_t cnt_gt = cntAbove + w;
  uint32_t r_ties = k - cnt_gt;
  uint32_t t_key = (a21 << 10) | (uint32_t)l;

  // collect ties, keep r_ties smallest flat indices (stable, as jax top_k)
  if (tid == 0){ sCnt[0] = 0u; sCnt[1] = 0u; sCnt[2] = 0u; }
  __syncthreads();
  for (uint32_t e = tid; e < cntP; e += 1024){
    uint64_t ent = slotBuf[e];
    uint32_t key = (uint32_t)(ent >> 32);
    if ((key & 1023u) == (uint32_t)l){
      uint32_t p = atomicAdd(&sCnt[0], 1u);
      if (p < MAX_TIES){ tieIdx[p] = (uint32_t)ent; tieSgn[p] = 1; }
    }
  }
  for (uint32_t e = tid; e < cntN; e += 1024){
    uint64_t ent = slotBuf[SLOT_CAP + e];
    uint32_t key = (uint32_t)(ent >> 32);
    uint32_t m = 0x7FFFFFFFu - key;
    if ((m & 1023u) == (uint32_t)l){
      uint32_t p = atomicAdd(&sCnt[0], 1u);
      if (p < MAX_TIES){ tieIdx[p] = (uint32_t)ent; tieSgn[p] = 0; }
    }
  }
  __syncthreads();
  uint32_t mT = sCnt[0]; if (mT > MAX_TIES) mT = MAX_TIES;
  for (uint32_t e = tid; e < mT; e += 1024){
    uint32_t my = tieIdx[e];
    uint32_t rank = 0;
    for (uint32_t f = 0; f < mT; f++) rank += (tieIdx[f] < my) ? 1u : 0u;
    if (rank < r_ties){
      uint32_t p = atomicAdd(&sCnt[1], 1u);
      if (p < MAX_TIES) ctl[CTL_TIEIDX + p] = my;
      if (tieSgn[e]) atomicAdd(&sCnt[2], 1u);
    }
  }
  __syncthreads();
  uint32_t nSel = sCnt[1]; if (nSel > MAX_TIES) nSel = MAX_TIES;
  uint32_t selPos = sCnt[2];

  // num_pos = #{x > |t|} + selected positive ties
  uint32_t part = 0;
  for (uint32_t e = tid; e < cntP; e += 1024){
    uint32_t key = (uint32_t)(slotBuf[e] >> 32);
    if ((key & 1023u) > (uint32_t)l) part++;
  }
  red[tid] = part;
  __syncthreads();
  for (int o = 512; o; o >>= 1){ if (tid < o) red[tid] += red[tid + o]; __syncthreads(); }
  uint32_t num_pos = red[0] + ctl[CTL_POSABOVE] + selPos;
  __syncthreads();

  // resolve 16 boundary values in parallel: wave wv handles boundary wv
  // (mx_p = kept rank p*c for wv<8; mn_{wv-8} = kept rank (wv-7)*c-1)
  {
    int wv = tid >> 6, ln = tid & 63;
    uint32_t kr = (wv < 8) ? (uint32_t)wv * c : (uint32_t)(wv - 7) * c - 1u;
    int cand = (kr < num_pos) ? wv : (16 + wv);
    uint32_t slot  = ctl[CTL_CANDSLOT + cand];
    uint32_t resid = ctl[CTL_CANDRES + cand];
    uint32_t bin   = ctl[CTL_SLOTBIN + slot];
    uint32_t cnt2  = slotCnt[slot]; if (cnt2 > SLOT_CAP) cnt2 = SLOT_CAP;
    uint32_t* h = bHist + wv * 1024;
    for (int j = ln; j < 1024; j += 64) h[j] = 0u;
    __syncthreads();
    for (uint32_t e = ln; e < cnt2; e += 64){
      uint32_t key = (uint32_t)(slotBuf[(size_t)slot * SLOT_CAP + e] >> 32);
      atomicAdd(&h[key & 1023u], 1u);
    }
    __syncthreads();
    // lane-local suffix over bins [ln*16, ln*16+16)
    uint32_t loc[16]; uint32_t lsuf = 0;
    #pragma unroll
    for (int j = 15; j >= 0; j--){ lsuf += h[ln * 16 + j]; loc[j] = lsuf; }
    uint32_t T = lsuf;
    uint32_t S = T;                       // inclusive suffix across lanes
    #pragma unroll
    for (int off = 1; off < 64; off <<= 1){
      uint32_t t2 = __shfl_down(S, off);
      if (ln + off < 64) S += t2;
    }
    uint32_t excl = S - T;                // sum over lanes > ln
    bool cross = (S > resid) && (excl <= resid);
    if (cross){
      int bl = 0;
      #pragma unroll
      for (int j = 15; j >= 0; j--){
        if (excl + loc[j] > resid){ bl = j; break; }
      }
      uint32_t fullkey = (bin << 10) | (uint32_t)(ln * 16 + bl);
      uint32_t bits = (fullkey & 0x80000000u) ? (fullkey ^ 0x80000000u) : ~fullkey;
      tvU[wv] = bits;
    }
  }
  __syncthreads();

  if (tid == 0){
    ctl[CTL_TKEY] = t_key;
    ctl[CTL_NTIES] = nSel;
    for (int j = 1; j < 8; j++) ctl[CTL_BND + (j - 1)] = tvU[j];   // b_j = mx_j
    for (int p = 0; p < 8; p++){
      float mx = __uint_as_float(tvU[p]), mn = __uint_as_float(tvU[8 + p]);
      ctl[CTL_MN + p] = tvU[8 + p];
      ctl[CTL_MX + p] = tvU[p];
      ctl[CTL_STEP + p] = __float_as_uint((mx - mn) / 255.0f);
    }
  }
}

// ---------------- pass 4: write quantized output ---------------------------
__global__ void k_out(const uint32_t* __restrict__ xb, float* __restrict__ out,
    const uint32_t* __restrict__ ctl, int n4){
  __shared__ float sB[7], sMn[8], sMx[8], sSt[8];
  __shared__ uint32_t sTK, sNT;
  __shared__ uint32_t sTie[MAX_TIES];
  int tid = threadIdx.x;
  if (tid == 0){ sTK = ctl[CTL_TKEY]; sNT = ctl[CTL_NTIES]; }
  if (tid < 7) sB[tid] = __uint_as_float(ctl[CTL_BND + tid]);
  if (tid < 8){
    sMn[tid] = __uint_as_float(ctl[CTL_MN + tid]);
    sMx[tid] = __uint_as_float(ctl[CTL_MX + tid]);
    sSt[tid] = __uint_as_float(ctl[CTL_STEP + tid]);
  }
  __syncthreads();
  uint32_t nt = sNT, tk = sTK;
  for (int e = tid; e < (int)nt; e += blockDim.x) sTie[e] = ctl[CTL_TIEIDX + e];
  __syncthreads();
  int i = blockIdx.x * blockDim.x + tid;
  if (i >= n4) return;
  uint4 v = ((const uint4*)xb)[i];
  uint32_t bv[4] = {v.x, v.y, v.z, v.w};
  float ov[4];
  uint32_t base = (uint32_t)i * 4u;
  #pragma unroll
  for (int j = 0; j < 4; j++){
    uint32_t b = bv[j];
    uint32_t m = b & 0x7FFFFFFFu;
    float q = 0.0f;
    bool keep = m > tk;
    if (m == tk){
      uint32_t idx = base + (uint32_t)j;
      for (uint32_t e = 0; e < nt; e++) if (sTie[e] == idx){ keep = true; break; }
    }
    if (keep){
      float x = __uint_as_float(b);
      int p = 0;
      #pragma unroll
      for (int j2 = 0; j2 < 7; j2++) p += (sB[j2] >= x) ? 1 : 0;
      float mn = sMn[p], mx = sMx[p], st = sSt[p];
      if (mn == mx) q = x;
      else {
        float sst = (st == 0.0f) ? 1.0f : st;
        q = rintf((x - mn) / sst) * st + mn;
      }
    }
    ov[j] = q;
  }
  ((float4*)out)[i] = make_float4(ov[0], ov[1], ov[2], ov[3]);
}

// ---------------------------------------------------------------------------
extern "C" void kernel_launch(void* const* d_in, const int* in_sizes, int n_in,
                              void* d_out, int out_size, void* d_ws, size_t ws_size,
                              hipStream_t stream){
  const uint32_t* xb = (const uint32_t*)d_in[0];
  float* out = (float*)d_out;
  uint32_t n = (uint32_t)in_sizes[0];
  uint32_t k = n / 4u;
  uint32_t c = k / 8u;

  // ws layout (u32 units)
  uint32_t* w = (uint32_t*)d_ws;
  uint32_t* H13     = w;                            // 8192
  uint32_t* H9      = H13 + H13BINS;                // 40*512 = 20480
  uint8_t*  table13 = (uint8_t*)(H9 + NSLOT_MAX*512); // 8192 B (2048 u32)
  uint32_t* ctl     = (uint32_t*)(table13 + H13BINS); // 1280
  uint32_t* htabG   = ctl + CTL_SIZE;               // 2048
  uint32_t* slotCnt = htabG + HTAB_SZ;              // 40
  uint64_t* slotBuf = (uint64_t*)(slotCnt + NSLOT_MAX); // 40*8192 u64
  uint32_t* part13  = (uint32_t*)(slotBuf + (size_t)NSLOT_MAX * SLOT_CAP);
  uint32_t* part9   = part13 + (size_t)P13 * H13BINS;
  size_t endu32 = (size_t)((uint32_t*)part9 - w) + (size_t)P9 * NSLOT_MAX * 512;
  if (ws_size < endu32 * 4u){
    hipMemsetAsync(d_out, 0, (size_t)out_size * 4u, stream);
    return;
  }

  int n4 = (int)(n / 4u);
  int blocksE = (n4 + 255) / 256;
  k_hist13<<<P13, 1024, 0, stream>>>(xb, part13, n4);
  k_red13 <<<H13BINS / 256, 256, 0, stream>>>(part13, H13);
  k_sel13 <<<1, 1024, 0, stream>>>(H13, ctl, table13, k, c, n);
  k_hist9 <<<P9, 1024, 0, stream>>>(xb, table13, ctl, part9, n4);
  k_red9  <<<(NSLOT_MAX * 512) / 256, 256, 0, stream>>>(part9, ctl, H9);
  k_sel9  <<<1, 1024, 0, stream>>>(H9, ctl, htabG, slotCnt);
  k_gather<<<GATHER_BLOCKS, 256, 0, stream>>>(xb, htabG, slotCnt, slotBuf, n4);
  k_s2    <<<1, 1024, 0, stream>>>(ctl, slotCnt, slotBuf, k, c);
  k_out   <<<blocksE, 256, 0, stream>>>(xb, out, ctl, n4);
}